// Round 10
// baseline (531.676 us; speedup 1.0000x reference)
//
#include <hip/hip_runtime.h>
#include <hip/hip_bf16.h>
#include <cstdint>

#define NN 100000
#define NE 1600000
#define NC 128

constexpr int NE4 = NE / 4;                 // 400000 int4-edge threads
constexpr int R   = 8;                      // counter replicas
constexpr int NR  = NN * R;                 // 800000 flat (node,replica) cells
constexpr int NB2 = (NR + 1023) / 1024;     // 782 scan blocks

// ---------------- bf16 helpers ----------------

__device__ __forceinline__ unsigned short f2bf(float f) {
    unsigned int u = __float_as_uint(f);
    u = (u + 0x7fffu + ((u >> 16) & 1u)) >> 16;   // RNE
    return (unsigned short)u;
}
#define BFLO(u) __uint_as_float((u) << 16)
#define BFHI(u) __uint_as_float((u) & 0xffff0000u)

// ---------------- CSR build: 8-way replicated counters ----------------
// cnt2 layout [r][NN] (replica-major, 400KB apart) -> atomic same-address
// collisions drop 8x. Flat CSR cell f = n*8 + r; row of node n = [rs2[8n], rs2[8n+8]).

__global__ __launch_bounds__(256) void k_init(int* __restrict__ cnt2) {
    int i = blockIdx.x * 256 + threadIdx.x;
    if (i < NR) cnt2[i] = 0;
}

__global__ __launch_bounds__(256) void k_count(const int4* __restrict__ dst4, int* __restrict__ cnt2,
                                               int4* __restrict__ slot4) {
    int i = blockIdx.x * 256 + threadIdx.x;
    if (i < NE4) {
        int* c = cnt2 + (i & 7) * NN;
        int4 d = dst4[i];
        int4 s;
        s.x = atomicAdd(&c[d.x], 1);
        s.y = atomicAdd(&c[d.y], 1);
        s.z = atomicAdd(&c[d.z], 1);
        s.w = atomicAdd(&c[d.w], 1);
        slot4[i] = s;
    }
}

// ---------------- exclusive scan of cnt2 (flat (n,r) order) -> rs2 ----------------

__global__ __launch_bounds__(256) void k_scan1(const int* __restrict__ cnt2, int* __restrict__ bsum) {
    __shared__ int sdata[256];
    int b = blockIdx.x, t = threadIdx.x;
    int base = b * 1024 + t * 4;
    int s = 0;
    #pragma unroll
    for (int j = 0; j < 4; ++j) {
        int f = base + j;
        if (f < NR) s += cnt2[(f & 7) * NN + (f >> 3)];
    }
    sdata[t] = s; __syncthreads();
    for (int off = 128; off > 0; off >>= 1) {
        if (t < off) sdata[t] += sdata[t + off];
        __syncthreads();
    }
    if (t == 0) bsum[b] = sdata[0];
}

// single-block scan over NB2 block sums (<=1024 entries)
__global__ __launch_bounds__(256) void k_scan2(int* __restrict__ bsum, int* __restrict__ rs2) {
    __shared__ int sdata[256];
    int t = threadIdx.x;
    int base = t * 4;
    int v[4]; int vsum = 0;
    #pragma unroll
    for (int j = 0; j < 4; ++j) { int idx = base + j; v[j] = (idx < NB2) ? bsum[idx] : 0; vsum += v[j]; }
    sdata[t] = vsum; __syncthreads();
    int incl = vsum;
    for (int off = 1; off < 256; off <<= 1) {
        int add = (t >= off) ? sdata[t - off] : 0;
        __syncthreads();
        incl += add;
        sdata[t] = incl;
        __syncthreads();
    }
    int run = incl - vsum;
    #pragma unroll
    for (int j = 0; j < 4; ++j) { int idx = base + j; if (idx < NB2) { bsum[idx] = run; run += v[j]; } }
    if (t == 255) rs2[NR] = run;   // == NE
}

__global__ __launch_bounds__(256) void k_scan3(const int* __restrict__ cnt2, const int* __restrict__ bsum,
                                               int* __restrict__ rs2) {
    __shared__ int sdata[256];
    int b = blockIdx.x, t = threadIdx.x;
    int base = b * 1024 + t * 4;
    int v[4]; int vsum = 0;
    #pragma unroll
    for (int j = 0; j < 4; ++j) {
        int f = base + j;
        v[j] = (f < NR) ? cnt2[(f & 7) * NN + (f >> 3)] : 0;
        vsum += v[j];
    }
    sdata[t] = vsum; __syncthreads();
    int incl = vsum;
    for (int off = 1; off < 256; off <<= 1) {
        int add = (t >= off) ? sdata[t - off] : 0;
        __syncthreads();
        incl += add;
        sdata[t] = incl;
        __syncthreads();
    }
    int run = bsum[b] + (incl - vsum);
    #pragma unroll
    for (int j = 0; j < 4; ++j) {
        int f = base + j;
        if (f < NR) { rs2[f] = run; run += v[j]; }
    }
}

// ---------------- CSR fill (no atomics): edat[pos] = {src, bits(RAW w)} ----------------

__global__ __launch_bounds__(256) void k_fill(const int4* __restrict__ src4, const int4* __restrict__ dst4,
                                              const float4* __restrict__ w4, const int* __restrict__ rs2,
                                              const int4* __restrict__ slot4, int2* __restrict__ edat) {
    int i = blockIdx.x * 256 + threadIdx.x;
    if (i < NE4) {
        int r = i & 7;
        int4 s = src4[i]; int4 d = dst4[i]; float4 wv = w4[i]; int4 sl = slot4[i];
        edat[rs2[d.x * R + r] + sl.x] = make_int2(s.x, __float_as_int(wv.x));
        edat[rs2[d.y * R + r] + sl.y] = make_int2(s.y, __float_as_int(wv.y));
        edat[rs2[d.z * R + r] + sl.z] = make_int2(s.z, __float_as_int(wv.z));
        edat[rs2[d.w * R + r] + sl.w] = make_int2(s.w, __float_as_int(wv.w));
    }
}

// ---------------- deg -> dinv (no atomics): deg = 1 + sum_row(w) ----------------

__global__ __launch_bounds__(256) void k_degdinv(const int* __restrict__ rs2, const int2* __restrict__ edat,
                                                 float* __restrict__ dinv) {
    int i = blockIdx.x * 256 + threadIdx.x;
    if (i < NN) {
        float dg = 1.0f;  // self-loop weight
        int p1 = rs2[i * R + R];
        for (int p = rs2[i * R]; p < p1; ++p) dg += __int_as_float(edat[p].y);
        dinv[i] = (dg > 0.0f) ? (1.0f / sqrtf(fmaxf(dg, 1e-12f))) : 0.0f;
    }
}

// ---------------- norm: edat[p].y = bits(dinv[src] * w)  (dinv[dst] applied in k_agg) ----------------

__global__ __launch_bounds__(256) void k_norm(const float* __restrict__ dinv, int2* __restrict__ edat) {
    int p = blockIdx.x * 256 + threadIdx.x;
    if (p < NE) {
        int2 ed = edat[p];
        edat[p].y = __float_as_int(dinv[ed.x] * __int_as_float(ed.y));
    }
}

// ---------------- GEMM: Hb = bf16(X @ W) ----------------
// 128x128 tile, 256 threads (16x16), 8 rows x 8 cols per thread; both operands
// in LDS (32 KB, kc=32); Xs transposed [k][row] -> conflict-free; W cols split
// {tx*4, 64+tx*4} -> 2-way bank alias (free).

__global__ __launch_bounds__(256) void k_gemm(const float* __restrict__ Xg, const float* __restrict__ Wg,
                                              unsigned short* __restrict__ Hb) {
    __shared__ float Xs[32][128];  // [k][row] 16 KB
    __shared__ float Ws[32][128];  // [k][col] 16 KB

    int t  = threadIdx.x;
    int tx = t & 15;
    int ty = t >> 4;
    int rowBase = blockIdx.x * 128;

    float4 accA[8], accB[8];
    #pragma unroll
    for (int r = 0; r < 8; ++r) { accA[r] = make_float4(0.f,0.f,0.f,0.f); accB[r] = accA[r]; }

    int lrow = t & 127;
    int lq   = t >> 7;
    int gr = rowBase + lrow; if (gr > NN - 1) gr = NN - 1;
    const float* xp = Xg + (size_t)gr * NC + lq * 16;

    for (int kc = 0; kc < 128; kc += 32) {
        float4 xa = *(const float4*)(xp + kc + 0);
        float4 xb = *(const float4*)(xp + kc + 4);
        float4 xc = *(const float4*)(xp + kc + 8);
        float4 xd = *(const float4*)(xp + kc + 12);
        float4 wl[4];
        #pragma unroll
        for (int j = 0; j < 4; ++j) {
            int l = (t + j * 256) * 4;
            wl[j] = *(const float4*)&Wg[(size_t)(kc + (l >> 7)) * NC + (l & 127)];
        }
        __syncthreads();
        int kb = lq * 16;
        Xs[kb+ 0][lrow] = xa.x; Xs[kb+ 1][lrow] = xa.y; Xs[kb+ 2][lrow] = xa.z; Xs[kb+ 3][lrow] = xa.w;
        Xs[kb+ 4][lrow] = xb.x; Xs[kb+ 5][lrow] = xb.y; Xs[kb+ 6][lrow] = xb.z; Xs[kb+ 7][lrow] = xb.w;
        Xs[kb+ 8][lrow] = xc.x; Xs[kb+ 9][lrow] = xc.y; Xs[kb+10][lrow] = xc.z; Xs[kb+11][lrow] = xc.w;
        Xs[kb+12][lrow] = xd.x; Xs[kb+13][lrow] = xd.y; Xs[kb+14][lrow] = xd.z; Xs[kb+15][lrow] = xd.w;
        #pragma unroll
        for (int j = 0; j < 4; ++j) {
            int l = (t + j * 256) * 4;
            *(float4*)&Ws[l >> 7][l & 127] = wl[j];
        }
        __syncthreads();

        #pragma unroll 8
        for (int k = 0; k < 32; ++k) {
            float4 wv0 = *(const float4*)&Ws[k][tx * 4];
            float4 wv1 = *(const float4*)&Ws[k][64 + tx * 4];
            float4 xv0 = *(const float4*)&Xs[k][ty * 8];
            float4 xv1 = *(const float4*)&Xs[k][ty * 8 + 4];
            float xs[8] = {xv0.x, xv0.y, xv0.z, xv0.w, xv1.x, xv1.y, xv1.z, xv1.w};
            #pragma unroll
            for (int r = 0; r < 8; ++r) {
                accA[r].x = fmaf(xs[r], wv0.x, accA[r].x);
                accA[r].y = fmaf(xs[r], wv0.y, accA[r].y);
                accA[r].z = fmaf(xs[r], wv0.z, accA[r].z);
                accA[r].w = fmaf(xs[r], wv0.w, accA[r].w);
                accB[r].x = fmaf(xs[r], wv1.x, accB[r].x);
                accB[r].y = fmaf(xs[r], wv1.y, accB[r].y);
                accB[r].z = fmaf(xs[r], wv1.z, accB[r].z);
                accB[r].w = fmaf(xs[r], wv1.w, accB[r].w);
            }
        }
    }

    #pragma unroll
    for (int r = 0; r < 8; ++r) {
        int grow = rowBase + ty * 8 + r;
        if (grow < NN) {
            ushort4 oa, ob;
            oa.x = f2bf(accA[r].x); oa.y = f2bf(accA[r].y); oa.z = f2bf(accA[r].z); oa.w = f2bf(accA[r].w);
            ob.x = f2bf(accB[r].x); ob.y = f2bf(accB[r].y); ob.z = f2bf(accB[r].z); ob.w = f2bf(accB[r].w);
            *(ushort4*)&Hb[(size_t)grow * NC + tx * 4]      = oa;
            *(ushort4*)&Hb[(size_t)grow * NC + 64 + tx * 4] = ob;
        }
    }
}

// ---------------- aggregation ----------------
// One 64-lane wave per node. 4 edge-groups x 16 lanes; each lane owns 8 channels
// (one dwordx4 of bf16 per edge). 4-way unrolled edge walk -> up to 16 edges in
// flight per wave. out[d] = dinv[d]*(sum_e nrm'*Hb[s] + dinv[d]*Hb[d]) + b.

#define AGG_FMA8(NW, U)                                                                    \
    do {                                                                                   \
        acc0.x = fmaf((NW), BFLO((U).x), acc0.x); acc0.y = fmaf((NW), BFHI((U).x), acc0.y);\
        acc0.z = fmaf((NW), BFLO((U).y), acc0.z); acc0.w = fmaf((NW), BFHI((U).y), acc0.w);\
        acc1.x = fmaf((NW), BFLO((U).z), acc1.x); acc1.y = fmaf((NW), BFHI((U).z), acc1.y);\
        acc1.z = fmaf((NW), BFLO((U).w), acc1.z); acc1.w = fmaf((NW), BFHI((U).w), acc1.w);\
    } while (0)

template <int RELU>
__global__ __launch_bounds__(256) void k_agg(const unsigned short* __restrict__ Hb, const int* __restrict__ rs2,
                                             const int2* __restrict__ edat,
                                             const float* __restrict__ dinv, const float* __restrict__ bias,
                                             float* __restrict__ out) {
    int wid  = (blockIdx.x * 256 + threadIdx.x) >> 6;
    int lane = threadIdx.x & 63;
    if (wid >= NN) return;
    int node = wid;
    int g  = lane >> 4;   // edge group 0..3
    int cl = lane & 15;   // channel lane: owns channels cl*8 .. cl*8+7

    float di = dinv[node];
    float4 acc0 = make_float4(0.f, 0.f, 0.f, 0.f);
    float4 acc1 = make_float4(0.f, 0.f, 0.f, 0.f);

    // self-loop contribution (before the final *di): di * H[node]
    if (g == 0) {
        uint4 U = *(const uint4*)(Hb + (size_t)node * NC + cl * 8);
        acc0.x = BFLO(U.x) * di; acc0.y = BFHI(U.x) * di;
        acc0.z = BFLO(U.y) * di; acc0.w = BFHI(U.y) * di;
        acc1.x = BFLO(U.z) * di; acc1.y = BFHI(U.z) * di;
        acc1.z = BFLO(U.w) * di; acc1.w = BFHI(U.w) * di;
    }

    int p0 = rs2[node * R], p1 = rs2[node * R + R];
    int p = p0 + g;
    for (; p + 12 < p1; p += 16) {
        long long r1 = __builtin_nontemporal_load((const long long*)&edat[p]);
        long long r2 = __builtin_nontemporal_load((const long long*)&edat[p + 4]);
        long long r3 = __builtin_nontemporal_load((const long long*)&edat[p + 8]);
        long long r4 = __builtin_nontemporal_load((const long long*)&edat[p + 12]);
        int   s1 = (int)(r1 & 0xffffffffLL);  float nw1 = __int_as_float((int)(r1 >> 32));
        int   s2 = (int)(r2 & 0xffffffffLL);  float nw2 = __int_as_float((int)(r2 >> 32));
        int   s3 = (int)(r3 & 0xffffffffLL);  float nw3 = __int_as_float((int)(r3 >> 32));
        int   s4 = (int)(r4 & 0xffffffffLL);  float nw4 = __int_as_float((int)(r4 >> 32));
        uint4 U1 = *(const uint4*)(Hb + (size_t)s1 * NC + cl * 8);
        uint4 U2 = *(const uint4*)(Hb + (size_t)s2 * NC + cl * 8);
        uint4 U3 = *(const uint4*)(Hb + (size_t)s3 * NC + cl * 8);
        uint4 U4 = *(const uint4*)(Hb + (size_t)s4 * NC + cl * 8);
        AGG_FMA8(nw1, U1);
        AGG_FMA8(nw2, U2);
        AGG_FMA8(nw3, U3);
        AGG_FMA8(nw4, U4);
    }
    for (; p < p1; p += 4) {
        long long r1 = __builtin_nontemporal_load((const long long*)&edat[p]);
        int   s1 = (int)(r1 & 0xffffffffLL);  float nw1 = __int_as_float((int)(r1 >> 32));
        uint4 U1 = *(const uint4*)(Hb + (size_t)s1 * NC + cl * 8);
        AGG_FMA8(nw1, U1);
    }

    // combine the 4 edge-groups: sum over lanes {cl, cl+16, cl+32, cl+48}
    #pragma unroll
    for (int m = 16; m <= 32; m <<= 1) {
        acc0.x += __shfl_xor(acc0.x, m); acc0.y += __shfl_xor(acc0.y, m);
        acc0.z += __shfl_xor(acc0.z, m); acc0.w += __shfl_xor(acc0.w, m);
        acc1.x += __shfl_xor(acc1.x, m); acc1.y += __shfl_xor(acc1.y, m);
        acc1.z += __shfl_xor(acc1.z, m); acc1.w += __shfl_xor(acc1.w, m);
    }

    if (g == 0) {
        const float4* bp = (const float4*)(bias + cl * 8);
        float4 bv0 = bp[0], bv1 = bp[1];
        acc0.x = fmaf(acc0.x, di, bv0.x); acc0.y = fmaf(acc0.y, di, bv0.y);
        acc0.z = fmaf(acc0.z, di, bv0.z); acc0.w = fmaf(acc0.w, di, bv0.w);
        acc1.x = fmaf(acc1.x, di, bv1.x); acc1.y = fmaf(acc1.y, di, bv1.y);
        acc1.z = fmaf(acc1.z, di, bv1.z); acc1.w = fmaf(acc1.w, di, bv1.w);
        if (RELU) {
            acc0.x = fmaxf(acc0.x, 0.f); acc0.y = fmaxf(acc0.y, 0.f);
            acc0.z = fmaxf(acc0.z, 0.f); acc0.w = fmaxf(acc0.w, 0.f);
            acc1.x = fmaxf(acc1.x, 0.f); acc1.y = fmaxf(acc1.y, 0.f);
            acc1.z = fmaxf(acc1.z, 0.f); acc1.w = fmaxf(acc1.w, 0.f);
        }
        float4* op = (float4*)(out + (size_t)node * NC + cl * 8);
        op[0] = acc0;
        op[1] = acc1;
    }
}

// ---------------- launch ----------------

static inline size_t alignup(size_t x) { return (x + 255) & ~(size_t)255; }

extern "C" void kernel_launch(void* const* d_in, const int* in_sizes, int n_in,
                              void* d_out, int out_size, void* d_ws, size_t ws_size,
                              hipStream_t stream) {
    const float* X  = (const float*)d_in[0];
    const int*   ei = (const int*)d_in[1];          // [2, NE]: row0 = src, row1 = dst
    const float* ew = (const float*)d_in[2];
    const float* W1 = (const float*)d_in[3]; const float* b1 = (const float*)d_in[4];
    const float* W2 = (const float*)d_in[5]; const float* b2 = (const float*)d_in[6];
    const float* W3 = (const float*)d_in[7]; const float* b3 = (const float*)d_in[8];
    float* out = (float*)d_out;

    const int* srcp = ei;
    const int* dstp = ei + NE;

    // workspace carve
    char* w = (char*)d_ws;
    size_t need = 0;
    auto carve = [&](size_t bytes) { char* p = w + need; need += alignup(bytes); return p; };
    float* dinv     = (float*)carve(NN * 4);
    int*   cnt2     = (int*)  carve((size_t)NR * 4);        // 3.2 MB
    int*   rs2      = (int*)  carve(((size_t)NR + 1) * 4);  // 3.2 MB
    int*   bsum     = (int*)  carve(NB2 * 4);
    int2*  edat     = (int2*) carve((size_t)NE * 8);
    unsigned short* Hb = (unsigned short*)carve((size_t)NN * NC * 2);
    float* A        = (float*)carve((size_t)NN * NC * 4);
    if (need > ws_size) return;  // workspace too small -> visible validation failure

    // slot (6.4 MB) aliases A: live only count->fill, while A is live only agg1 onward
    int* slot = (int*)A;

    const int gN   = (NN + 255) / 256;
    const int gNR  = (NR + 255) / 256;
    const int gE   = (NE + 255) / 256;
    const int gE4  = (NE4 + 255) / 256;
    const int gGemm = (NN + 127) / 128;
    const int gAgg  = (NN * 64 + 255) / 256;  // one wave per node

    // CSR build with replicated counters
    k_init<<<gNR, 256, 0, stream>>>(cnt2);
    k_count<<<gE4, 256, 0, stream>>>((const int4*)dstp, cnt2, (int4*)slot);
    k_scan1<<<NB2, 256, 0, stream>>>(cnt2, bsum);
    k_scan2<<<1, 256, 0, stream>>>(bsum, rs2);
    k_scan3<<<NB2, 256, 0, stream>>>(cnt2, bsum, rs2);
    k_fill<<<gE4, 256, 0, stream>>>((const int4*)srcp, (const int4*)dstp, (const float4*)ew,
                                    rs2, (const int4*)slot, edat);
    k_degdinv<<<gN, 256, 0, stream>>>(rs2, edat, dinv);
    k_norm<<<gE, 256, 0, stream>>>(dinv, edat);

    // layer 1
    k_gemm<<<gGemm, 256, 0, stream>>>(X, W1, Hb);
    k_agg<1><<<gAgg, 256, 0, stream>>>(Hb, rs2, edat, dinv, b1, A);
    // layer 2
    k_gemm<<<gGemm, 256, 0, stream>>>(A, W2, Hb);
    k_agg<1><<<gAgg, 256, 0, stream>>>(Hb, rs2, edat, dinv, b2, A);
    // layer 3
    k_gemm<<<gGemm, 256, 0, stream>>>(A, W3, Hb);
    k_agg<0><<<gAgg, 256, 0, stream>>>(Hb, rs2, edat, dinv, b3, out);
}

// Round 11
// 494.826 us; speedup vs baseline: 1.0745x; 1.0745x over previous
//
#include <hip/hip_runtime.h>
#include <hip/hip_bf16.h>
#include <cstdint>

#define NN 100000
#define NE 1600000
#define NC 128

constexpr int SCAN_SEG = 1024;
constexpr int NB = (NN + SCAN_SEG - 1) / SCAN_SEG; // 98
constexpr int GGEMM = (NN + 127) / 128;            // 782
constexpr int CTHREADS = GGEMM * 256;              // 200192 count threads
constexpr int NE4 = NE / 4;                        // 400000

// ---------------- bf16 helpers ----------------

__device__ __forceinline__ unsigned short f2bf(float f) {
    unsigned int u = __float_as_uint(f);
    u = (u + 0x7fffu + ((u >> 16) & 1u)) >> 16;   // RNE
    return (unsigned short)u;
}
#define BFLO(u) __uint_as_float((u) << 16)
#define BFHI(u) __uint_as_float((u) & 0xffff0000u)

// ---------------- CSR build ----------------

__global__ __launch_bounds__(256) void k_init(int* __restrict__ cnt) {
    int i = blockIdx.x * 256 + threadIdx.x;
    if (i < NN) cnt[i] = 0;
}

// ---------------- fused: layer-1 GEMM with self-contained count prologue ----------------

__global__ __launch_bounds__(256) void k_gemm1c(const float* __restrict__ Xg, const float* __restrict__ Wg,
                                                unsigned short* __restrict__ Hb,
                                                const int4* __restrict__ dst4, int* __restrict__ cnt,
                                                int4* __restrict__ slot4) {
    __shared__ float Xs[32][128];  // [k][row] 16 KB
    __shared__ float Ws[32][128];  // [k][col] 16 KB

    int t   = threadIdx.x;
    int tid = blockIdx.x * 256 + t;

    // count prologue (self-contained: slots written immediately, no state held)
    {
        int4 d = dst4[tid];
        int4 s;
        s.x = atomicAdd(&cnt[d.x], 1);
        s.y = atomicAdd(&cnt[d.y], 1);
        s.z = atomicAdd(&cnt[d.z], 1);
        s.w = atomicAdd(&cnt[d.w], 1);
        slot4[tid] = s;
    }
    if (tid + CTHREADS < NE4) {
        int4 d = dst4[tid + CTHREADS];
        int4 s;
        s.x = atomicAdd(&cnt[d.x], 1);
        s.y = atomicAdd(&cnt[d.y], 1);
        s.z = atomicAdd(&cnt[d.z], 1);
        s.w = atomicAdd(&cnt[d.w], 1);
        slot4[tid + CTHREADS] = s;
    }

    int tx = t & 15;
    int ty = t >> 4;
    int rowBase = blockIdx.x * 128;

    float4 accA[8], accB[8];
    #pragma unroll
    for (int r = 0; r < 8; ++r) { accA[r] = make_float4(0.f,0.f,0.f,0.f); accB[r] = accA[r]; }

    int lrow = t & 127;
    int lq   = t >> 7;
    int gr = rowBase + lrow; if (gr > NN - 1) gr = NN - 1;
    const float* xp = Xg + (size_t)gr * NC + lq * 16;

    for (int kc = 0; kc < 128; kc += 32) {
        float4 xa = *(const float4*)(xp + kc + 0);
        float4 xb = *(const float4*)(xp + kc + 4);
        float4 xc = *(const float4*)(xp + kc + 8);
        float4 xd = *(const float4*)(xp + kc + 12);
        float4 wl[4];
        #pragma unroll
        for (int j = 0; j < 4; ++j) {
            int l = (t + j * 256) * 4;
            wl[j] = *(const float4*)&Wg[(size_t)(kc + (l >> 7)) * NC + (l & 127)];
        }
        __syncthreads();
        int kb = lq * 16;
        Xs[kb+ 0][lrow] = xa.x; Xs[kb+ 1][lrow] = xa.y; Xs[kb+ 2][lrow] = xa.z; Xs[kb+ 3][lrow] = xa.w;
        Xs[kb+ 4][lrow] = xb.x; Xs[kb+ 5][lrow] = xb.y; Xs[kb+ 6][lrow] = xb.z; Xs[kb+ 7][lrow] = xb.w;
        Xs[kb+ 8][lrow] = xc.x; Xs[kb+ 9][lrow] = xc.y; Xs[kb+10][lrow] = xc.z; Xs[kb+11][lrow] = xc.w;
        Xs[kb+12][lrow] = xd.x; Xs[kb+13][lrow] = xd.y; Xs[kb+14][lrow] = xd.z; Xs[kb+15][lrow] = xd.w;
        #pragma unroll
        for (int j = 0; j < 4; ++j) {
            int l = (t + j * 256) * 4;
            *(float4*)&Ws[l >> 7][l & 127] = wl[j];
        }
        __syncthreads();

        #pragma unroll 8
        for (int k = 0; k < 32; ++k) {
            float4 wv0 = *(const float4*)&Ws[k][tx * 4];
            float4 wv1 = *(const float4*)&Ws[k][64 + tx * 4];
            float4 xv0 = *(const float4*)&Xs[k][ty * 8];
            float4 xv1 = *(const float4*)&Xs[k][ty * 8 + 4];
            float xs[8] = {xv0.x, xv0.y, xv0.z, xv0.w, xv1.x, xv1.y, xv1.z, xv1.w};
            #pragma unroll
            for (int r = 0; r < 8; ++r) {
                accA[r].x = fmaf(xs[r], wv0.x, accA[r].x);
                accA[r].y = fmaf(xs[r], wv0.y, accA[r].y);
                accA[r].z = fmaf(xs[r], wv0.z, accA[r].z);
                accA[r].w = fmaf(xs[r], wv0.w, accA[r].w);
                accB[r].x = fmaf(xs[r], wv1.x, accB[r].x);
                accB[r].y = fmaf(xs[r], wv1.y, accB[r].y);
                accB[r].z = fmaf(xs[r], wv1.z, accB[r].z);
                accB[r].w = fmaf(xs[r], wv1.w, accB[r].w);
            }
        }
    }

    #pragma unroll
    for (int r = 0; r < 8; ++r) {
        int grow = rowBase + ty * 8 + r;
        if (grow < NN) {
            ushort4 oa, ob;
            oa.x = f2bf(accA[r].x); oa.y = f2bf(accA[r].y); oa.z = f2bf(accA[r].z); oa.w = f2bf(accA[r].w);
            ob.x = f2bf(accB[r].x); ob.y = f2bf(accB[r].y); ob.z = f2bf(accB[r].z); ob.w = f2bf(accB[r].w);
            *(ushort4*)&Hb[(size_t)grow * NC + tx * 4]      = oa;
            *(ushort4*)&Hb[(size_t)grow * NC + 64 + tx * 4] = ob;
        }
    }
}

// ---------------- exclusive scan of cnt -> rowstart ----------------

__global__ __launch_bounds__(256) void k_scan1(const int* __restrict__ cnt, int* __restrict__ bsum) {
    __shared__ int sdata[256];
    int b = blockIdx.x, t = threadIdx.x;
    int base = b * SCAN_SEG + t * 4;
    int s = 0;
    #pragma unroll
    for (int j = 0; j < 4; ++j) { int idx = base + j; if (idx < NN) s += cnt[idx]; }
    sdata[t] = s; __syncthreads();
    for (int off = 128; off > 0; off >>= 1) {
        if (t < off) sdata[t] += sdata[t + off];
        __syncthreads();
    }
    if (t == 0) bsum[b] = sdata[0];
}

__global__ void k_scan2(int* __restrict__ bsum, int* __restrict__ rowstart) {
    if (threadIdx.x == 0 && blockIdx.x == 0) {
        int run = 0;
        for (int i = 0; i < NB; ++i) { int v = bsum[i]; bsum[i] = run; run += v; }
        rowstart[NN] = run;  // == NE
    }
}

__global__ __launch_bounds__(256) void k_scan3(const int* __restrict__ cnt, const int* __restrict__ bsum,
                                               int* __restrict__ rowstart) {
    __shared__ int sdata[256];
    int b = blockIdx.x, t = threadIdx.x;
    int base = b * SCAN_SEG + t * 4;
    int v[4]; int vsum = 0;
    #pragma unroll
    for (int j = 0; j < 4; ++j) { int idx = base + j; v[j] = (idx < NN) ? cnt[idx] : 0; vsum += v[j]; }
    sdata[t] = vsum; __syncthreads();
    int incl = vsum;
    for (int off = 1; off < 256; off <<= 1) {
        int add = (t >= off) ? sdata[t - off] : 0;
        __syncthreads();
        incl += add;
        sdata[t] = incl;
        __syncthreads();
    }
    int run = bsum[b] + (incl - vsum);
    #pragma unroll
    for (int j = 0; j < 4; ++j) {
        int idx = base + j;
        if (idx < NN) { rowstart[idx] = run; run += v[j]; }
    }
}

// ---------------- CSR fill (no atomics): edat[pos] = {src, bits(RAW w)} ----------------

__global__ __launch_bounds__(256) void k_fill(const int4* __restrict__ src4, const int4* __restrict__ dst4,
                                              const float4* __restrict__ w4, const int* __restrict__ rowstart,
                                              const int4* __restrict__ slot4, int2* __restrict__ edat) {
    int i = blockIdx.x * 256 + threadIdx.x;
    if (i < NE4) {
        int4 s = src4[i]; int4 d = dst4[i]; float4 wv = w4[i]; int4 sl = slot4[i];
        edat[rowstart[d.x] + sl.x] = make_int2(s.x, __float_as_int(wv.x));
        edat[rowstart[d.y] + sl.y] = make_int2(s.y, __float_as_int(wv.y));
        edat[rowstart[d.z] + sl.z] = make_int2(s.z, __float_as_int(wv.z));
        edat[rowstart[d.w] + sl.w] = make_int2(s.w, __float_as_int(wv.w));
    }
}

// ---------------- deg -> dinv (no atomics): deg = 1 + sum_row(w) ----------------

__global__ __launch_bounds__(256) void k_degdinv(const int* __restrict__ rs, const int2* __restrict__ edat,
                                                 float* __restrict__ dinv) {
    int i = blockIdx.x * 256 + threadIdx.x;
    if (i < NN) {
        float dg = 1.0f;  // self-loop weight
        int p1 = rs[i + 1];
        for (int p = rs[i]; p < p1; ++p) dg += __int_as_float(edat[p].y);
        dinv[i] = (dg > 0.0f) ? (1.0f / sqrtf(fmaxf(dg, 1e-12f))) : 0.0f;
    }
}

// ---------------- norm: edat[p].y = bits(dinv[src] * w)  (dinv[dst] applied in k_agg) ----------------

__global__ __launch_bounds__(256) void k_norm(const float* __restrict__ dinv, int2* __restrict__ edat) {
    int p = blockIdx.x * 256 + threadIdx.x;
    if (p < NE) {
        int2 ed = edat[p];
        edat[p].y = __float_as_int(dinv[ed.x] * __int_as_float(ed.y));
    }
}

// ---------------- GEMM: Hb = bf16(X @ W) (layers 2,3) ----------------

__global__ __launch_bounds__(256) void k_gemm(const float* __restrict__ Xg, const float* __restrict__ Wg,
                                              unsigned short* __restrict__ Hb) {
    __shared__ float Xs[32][128];  // [k][row] 16 KB
    __shared__ float Ws[32][128];  // [k][col] 16 KB

    int t  = threadIdx.x;
    int tx = t & 15;
    int ty = t >> 4;
    int rowBase = blockIdx.x * 128;

    float4 accA[8], accB[8];
    #pragma unroll
    for (int r = 0; r < 8; ++r) { accA[r] = make_float4(0.f,0.f,0.f,0.f); accB[r] = accA[r]; }

    int lrow = t & 127;
    int lq   = t >> 7;
    int gr = rowBase + lrow; if (gr > NN - 1) gr = NN - 1;
    const float* xp = Xg + (size_t)gr * NC + lq * 16;

    for (int kc = 0; kc < 128; kc += 32) {
        float4 xa = *(const float4*)(xp + kc + 0);
        float4 xb = *(const float4*)(xp + kc + 4);
        float4 xc = *(const float4*)(xp + kc + 8);
        float4 xd = *(const float4*)(xp + kc + 12);
        float4 wl[4];
        #pragma unroll
        for (int j = 0; j < 4; ++j) {
            int l = (t + j * 256) * 4;
            wl[j] = *(const float4*)&Wg[(size_t)(kc + (l >> 7)) * NC + (l & 127)];
        }
        __syncthreads();
        int kb = lq * 16;
        Xs[kb+ 0][lrow] = xa.x; Xs[kb+ 1][lrow] = xa.y; Xs[kb+ 2][lrow] = xa.z; Xs[kb+ 3][lrow] = xa.w;
        Xs[kb+ 4][lrow] = xb.x; Xs[kb+ 5][lrow] = xb.y; Xs[kb+ 6][lrow] = xb.z; Xs[kb+ 7][lrow] = xb.w;
        Xs[kb+ 8][lrow] = xc.x; Xs[kb+ 9][lrow] = xc.y; Xs[kb+10][lrow] = xc.z; Xs[kb+11][lrow] = xc.w;
        Xs[kb+12][lrow] = xd.x; Xs[kb+13][lrow] = xd.y; Xs[kb+14][lrow] = xd.z; Xs[kb+15][lrow] = xd.w;
        #pragma unroll
        for (int j = 0; j < 4; ++j) {
            int l = (t + j * 256) * 4;
            *(float4*)&Ws[l >> 7][l & 127] = wl[j];
        }
        __syncthreads();

        #pragma unroll 8
        for (int k = 0; k < 32; ++k) {
            float4 wv0 = *(const float4*)&Ws[k][tx * 4];
            float4 wv1 = *(const float4*)&Ws[k][64 + tx * 4];
            float4 xv0 = *(const float4*)&Xs[k][ty * 8];
            float4 xv1 = *(const float4*)&Xs[k][ty * 8 + 4];
            float xs[8] = {xv0.x, xv0.y, xv0.z, xv0.w, xv1.x, xv1.y, xv1.z, xv1.w};
            #pragma unroll
            for (int r = 0; r < 8; ++r) {
                accA[r].x = fmaf(xs[r], wv0.x, accA[r].x);
                accA[r].y = fmaf(xs[r], wv0.y, accA[r].y);
                accA[r].z = fmaf(xs[r], wv0.z, accA[r].z);
                accA[r].w = fmaf(xs[r], wv0.w, accA[r].w);
                accB[r].x = fmaf(xs[r], wv1.x, accB[r].x);
                accB[r].y = fmaf(xs[r], wv1.y, accB[r].y);
                accB[r].z = fmaf(xs[r], wv1.z, accB[r].z);
                accB[r].w = fmaf(xs[r], wv1.w, accB[r].w);
            }
        }
    }

    #pragma unroll
    for (int r = 0; r < 8; ++r) {
        int grow = rowBase + ty * 8 + r;
        if (grow < NN) {
            ushort4 oa, ob;
            oa.x = f2bf(accA[r].x); oa.y = f2bf(accA[r].y); oa.z = f2bf(accA[r].z); oa.w = f2bf(accA[r].w);
            ob.x = f2bf(accB[r].x); ob.y = f2bf(accB[r].y); ob.z = f2bf(accB[r].z); ob.w = f2bf(accB[r].w);
            *(ushort4*)&Hb[(size_t)grow * NC + tx * 4]      = oa;
            *(ushort4*)&Hb[(size_t)grow * NC + 64 + tx * 4] = ob;
        }
    }
}

// ---------------- aggregation ----------------
// One 16-lane group OWNS one node (16 nodes per 256-thread block). Serial row
// walk, 4-deep unroll over CONSECUTIVE CSR slots (edat[p..p+3], contiguous 32B)
// -> 4 H-row gathers in flight per group for every row >= 4; no cross-group
// shuffles, no lane masking. out[d] = dinv[d]*(sum nrm'*Hb[s] + dinv[d]*Hb[d]) + b.

#define AGG_FMA8(NW, U)                                                                    \
    do {                                                                                   \
        acc0.x = fmaf((NW), BFLO((U).x), acc0.x); acc0.y = fmaf((NW), BFHI((U).x), acc0.y);\
        acc0.z = fmaf((NW), BFLO((U).y), acc0.z); acc0.w = fmaf((NW), BFHI((U).y), acc0.w);\
        acc1.x = fmaf((NW), BFLO((U).z), acc1.x); acc1.y = fmaf((NW), BFHI((U).z), acc1.y);\
        acc1.z = fmaf((NW), BFLO((U).w), acc1.z); acc1.w = fmaf((NW), BFHI((U).w), acc1.w);\
    } while (0)

template <int RELU>
__global__ __launch_bounds__(256) void k_agg(const unsigned short* __restrict__ Hb, const int* __restrict__ rs,
                                             const int2* __restrict__ edat,
                                             const float* __restrict__ dinv, const float* __restrict__ bias,
                                             float* __restrict__ out) {
    int node = (blockIdx.x * 256 + threadIdx.x) >> 4;
    int cl   = threadIdx.x & 15;   // channel lane: owns channels cl*8 .. cl*8+7
    if (node >= NN) return;

    float di = dinv[node];
    float4 acc0, acc1;

    // self-loop contribution (before the final *di): di * H[node]
    {
        uint4 U = *(const uint4*)(Hb + (size_t)node * NC + cl * 8);
        acc0.x = BFLO(U.x) * di; acc0.y = BFHI(U.x) * di;
        acc0.z = BFLO(U.y) * di; acc0.w = BFHI(U.y) * di;
        acc1.x = BFLO(U.z) * di; acc1.y = BFHI(U.z) * di;
        acc1.z = BFLO(U.w) * di; acc1.w = BFHI(U.w) * di;
    }

    int p0 = rs[node], p1 = rs[node + 1];
    int p = p0;
    for (; p + 3 < p1; p += 4) {
        long long r1 = __builtin_nontemporal_load((const long long*)&edat[p + 0]);
        long long r2 = __builtin_nontemporal_load((const long long*)&edat[p + 1]);
        long long r3 = __builtin_nontemporal_load((const long long*)&edat[p + 2]);
        long long r4 = __builtin_nontemporal_load((const long long*)&edat[p + 3]);
        int   s1 = (int)(r1 & 0xffffffffLL);  float nw1 = __int_as_float((int)(r1 >> 32));
        int   s2 = (int)(r2 & 0xffffffffLL);  float nw2 = __int_as_float((int)(r2 >> 32));
        int   s3 = (int)(r3 & 0xffffffffLL);  float nw3 = __int_as_float((int)(r3 >> 32));
        int   s4 = (int)(r4 & 0xffffffffLL);  float nw4 = __int_as_float((int)(r4 >> 32));
        uint4 U1 = *(const uint4*)(Hb + (size_t)s1 * NC + cl * 8);
        uint4 U2 = *(const uint4*)(Hb + (size_t)s2 * NC + cl * 8);
        uint4 U3 = *(const uint4*)(Hb + (size_t)s3 * NC + cl * 8);
        uint4 U4 = *(const uint4*)(Hb + (size_t)s4 * NC + cl * 8);
        AGG_FMA8(nw1, U1);
        AGG_FMA8(nw2, U2);
        AGG_FMA8(nw3, U3);
        AGG_FMA8(nw4, U4);
    }
    for (; p < p1; ++p) {
        long long r1 = __builtin_nontemporal_load((const long long*)&edat[p]);
        int   s1 = (int)(r1 & 0xffffffffLL);  float nw1 = __int_as_float((int)(r1 >> 32));
        uint4 U1 = *(const uint4*)(Hb + (size_t)s1 * NC + cl * 8);
        AGG_FMA8(nw1, U1);
    }

    const float4* bp = (const float4*)(bias + cl * 8);
    float4 bv0 = bp[0], bv1 = bp[1];
    acc0.x = fmaf(acc0.x, di, bv0.x); acc0.y = fmaf(acc0.y, di, bv0.y);
    acc0.z = fmaf(acc0.z, di, bv0.z); acc0.w = fmaf(acc0.w, di, bv0.w);
    acc1.x = fmaf(acc1.x, di, bv1.x); acc1.y = fmaf(acc1.y, di, bv1.y);
    acc1.z = fmaf(acc1.z, di, bv1.z); acc1.w = fmaf(acc1.w, di, bv1.w);
    if (RELU) {
        acc0.x = fmaxf(acc0.x, 0.f); acc0.y = fmaxf(acc0.y, 0.f);
        acc0.z = fmaxf(acc0.z, 0.f); acc0.w = fmaxf(acc0.w, 0.f);
        acc1.x = fmaxf(acc1.x, 0.f); acc1.y = fmaxf(acc1.y, 0.f);
        acc1.z = fmaxf(acc1.z, 0.f); acc1.w = fmaxf(acc1.w, 0.f);
    }
    float4* op = (float4*)(out + (size_t)node * NC + cl * 8);
    op[0] = acc0;
    op[1] = acc1;
}

// ---------------- launch ----------------

static inline size_t alignup(size_t x) { return (x + 255) & ~(size_t)255; }

extern "C" void kernel_launch(void* const* d_in, const int* in_sizes, int n_in,
                              void* d_out, int out_size, void* d_ws, size_t ws_size,
                              hipStream_t stream) {
    const float* X  = (const float*)d_in[0];
    const int*   ei = (const int*)d_in[1];          // [2, NE]: row0 = src, row1 = dst
    const float* ew = (const float*)d_in[2];
    const float* W1 = (const float*)d_in[3]; const float* b1 = (const float*)d_in[4];
    const float* W2 = (const float*)d_in[5]; const float* b2 = (const float*)d_in[6];
    const float* W3 = (const float*)d_in[7]; const float* b3 = (const float*)d_in[8];
    float* out = (float*)d_out;

    const int* srcp = ei;
    const int* dstp = ei + NE;

    // workspace carve
    char* w = (char*)d_ws;
    size_t need = 0;
    auto carve = [&](size_t bytes) { char* p = w + need; need += alignup(bytes); return p; };
    float* dinv     = (float*)carve(NN * 4);
    int*   cnt      = (int*)  carve(NN * 4);
    int*   rowstart = (int*)  carve((NN + 1) * 4);
    int*   bsum     = (int*)  carve(NB * 4);
    int*   slot     = (int*)  carve((size_t)NE * 4);
    int2*  edat     = (int2*) carve((size_t)NE * 8);
    unsigned short* Hb = (unsigned short*)carve((size_t)NN * NC * 2);
    float* A        = (float*)carve((size_t)NN * NC * 4);
    if (need > ws_size) return;  // workspace too small -> visible validation failure

    const int gN  = (NN + 255) / 256;
    const int gE  = (NE + 255) / 256;
    const int gE4 = (NE4 + 255) / 256;
    const int gAgg = (NN * 16 + 255) / 256;  // one 16-lane group per node

    // CSR count overlapped with layer-1 GEMM (self-contained prologue)
    k_init<<<gN, 256, 0, stream>>>(cnt);
    k_gemm1c<<<GGEMM, 256, 0, stream>>>(X, W1, Hb, (const int4*)dstp, cnt, (int4*)slot);
    k_scan1<<<NB, 256, 0, stream>>>(cnt, bsum);
    k_scan2<<<1, 64, 0, stream>>>(bsum, rowstart);
    k_scan3<<<NB, 256, 0, stream>>>(cnt, bsum, rowstart);
    k_fill<<<gE4, 256, 0, stream>>>((const int4*)srcp, (const int4*)dstp, (const float4*)ew,
                                    rowstart, (const int4*)slot, edat);
    k_degdinv<<<gN, 256, 0, stream>>>(rowstart, edat, dinv);
    k_norm<<<gE, 256, 0, stream>>>(dinv, edat);

    // layer 1 aggregation
    k_agg<1><<<gAgg, 256, 0, stream>>>(Hb, rowstart, edat, dinv, b1, A);
    // layer 2
    k_gemm<<<GGEMM, 256, 0, stream>>>(A, W2, Hb);
    k_agg<1><<<gAgg, 256, 0, stream>>>(Hb, rowstart, edat, dinv, b2, A);
    // layer 3
    k_gemm<<<GGEMM, 256, 0, stream>>>(A, W3, Hb);
    k_agg<0><<<gAgg, 256, 0, stream>>>(Hb, rowstart, edat, dinv, b3, out);
}

// Round 12
// 416.823 us; speedup vs baseline: 1.2755x; 1.1871x over previous
//
#include <hip/hip_runtime.h>
#include <hip/hip_bf16.h>
#include <cstdint>

#define NN 100000
#define NE 1600000
#define NC 128

constexpr int SCAN_SEG = 1024;
constexpr int NB = (NN + SCAN_SEG - 1) / SCAN_SEG; // 98
constexpr int NE4 = NE / 4;                        // 400000 (== NN*128/32: each count thread converts 32 X elems)

typedef __attribute__((ext_vector_type(8))) short short8;
typedef __attribute__((ext_vector_type(4))) float f32x4;

// ---------------- bf16 helpers ----------------

__device__ __forceinline__ unsigned int f2bf(float f) {
    unsigned int u = __float_as_uint(f);
    u = (u + 0x7fffu + ((u >> 16) & 1u)) >> 16;   // RNE
    return u & 0xffffu;
}
#define BFLO(u) __uint_as_float((u) << 16)
#define BFHI(u) __uint_as_float((u) & 0xffff0000u)

// ---------------- CSR build ----------------

__global__ __launch_bounds__(256) void k_init(int* __restrict__ cnt) {
    int i = blockIdx.x * 256 + threadIdx.x;
    if (i < NN) cnt[i] = 0;
}

// count atomics + slot write, with X->bf16 conversion folded into the
// atomic-latency shadow (issue atomics -> convert 32 elems -> write slots).
__global__ __launch_bounds__(256) void k_count(const int4* __restrict__ dst4, int* __restrict__ cnt,
                                               int4* __restrict__ slot4,
                                               const float4* __restrict__ X4, uint4* __restrict__ Xb4) {
    int i = blockIdx.x * 256 + threadIdx.x;
    if (i >= NE4) return;
    int4 d = dst4[i];
    int4 s;
    s.x = atomicAdd(&cnt[d.x], 1);
    s.y = atomicAdd(&cnt[d.y], 1);
    s.z = atomicAdd(&cnt[d.z], 1);
    s.w = atomicAdd(&cnt[d.w], 1);
    // conversion work overlaps the atomic returns
    #pragma unroll
    for (int c = 0; c < 4; ++c) {
        float4 u = X4[(size_t)i * 8 + c * 2];
        float4 v = X4[(size_t)i * 8 + c * 2 + 1];
        uint4 o;
        o.x = f2bf(u.x) | (f2bf(u.y) << 16);
        o.y = f2bf(u.z) | (f2bf(u.w) << 16);
        o.z = f2bf(v.x) | (f2bf(v.y) << 16);
        o.w = f2bf(v.z) | (f2bf(v.w) << 16);
        Xb4[(size_t)i * 4 + c] = o;
    }
    slot4[i] = s;
}

// ---------------- W -> fragment-swizzled bf16 ----------------
// Wb frag (ks,ct): 64 lanes x 8 bf16; lane l holds W[ks*32+(l>>4)*8+j][ct*16+(l&15)].
// Flat bf16 offset: ((ks*8+ct)*64 + l)*8 + j.

__global__ __launch_bounds__(256) void k_wconv(const float* __restrict__ W, unsigned short* __restrict__ Wb) {
    int j = blockIdx.x * 256 + threadIdx.x;
    if (j >= 2048) return;
    int f = j >> 6, l = j & 63;
    int ks = f >> 3, ct = f & 7;
    int kb  = ks * 32 + (l >> 4) * 8;
    int col = ct * 16 + (l & 15);
    uint4 o;
    o.x = f2bf(W[(size_t)(kb + 0) * NC + col]) | (f2bf(W[(size_t)(kb + 1) * NC + col]) << 16);
    o.y = f2bf(W[(size_t)(kb + 2) * NC + col]) | (f2bf(W[(size_t)(kb + 3) * NC + col]) << 16);
    o.z = f2bf(W[(size_t)(kb + 4) * NC + col]) | (f2bf(W[(size_t)(kb + 5) * NC + col]) << 16);
    o.w = f2bf(W[(size_t)(kb + 6) * NC + col]) | (f2bf(W[(size_t)(kb + 7) * NC + col]) << 16);
    *(uint4*)(Wb + (size_t)j * 8) = o;
}

// ---------------- exclusive scan of cnt -> rowstart ----------------

__global__ __launch_bounds__(256) void k_scan1(const int* __restrict__ cnt, int* __restrict__ bsum) {
    __shared__ int sdata[256];
    int b = blockIdx.x, t = threadIdx.x;
    int base = b * SCAN_SEG + t * 4;
    int s = 0;
    #pragma unroll
    for (int j = 0; j < 4; ++j) { int idx = base + j; if (idx < NN) s += cnt[idx]; }
    sdata[t] = s; __syncthreads();
    for (int off = 128; off > 0; off >>= 1) {
        if (t < off) sdata[t] += sdata[t + off];
        __syncthreads();
    }
    if (t == 0) bsum[b] = sdata[0];
}

__global__ void k_scan2(int* __restrict__ bsum, int* __restrict__ rowstart) {
    if (threadIdx.x == 0 && blockIdx.x == 0) {
        int run = 0;
        for (int i = 0; i < NB; ++i) { int v = bsum[i]; bsum[i] = run; run += v; }
        rowstart[NN] = run;  // == NE
    }
}

__global__ __launch_bounds__(256) void k_scan3(const int* __restrict__ cnt, const int* __restrict__ bsum,
                                               int* __restrict__ rowstart) {
    __shared__ int sdata[256];
    int b = blockIdx.x, t = threadIdx.x;
    int base = b * SCAN_SEG + t * 4;
    int v[4]; int vsum = 0;
    #pragma unroll
    for (int j = 0; j < 4; ++j) { int idx = base + j; v[j] = (idx < NN) ? cnt[idx] : 0; vsum += v[j]; }
    sdata[t] = vsum; __syncthreads();
    int incl = vsum;
    for (int off = 1; off < 256; off <<= 1) {
        int add = (t >= off) ? sdata[t - off] : 0;
        __syncthreads();
        incl += add;
        sdata[t] = incl;
        __syncthreads();
    }
    int run = bsum[b] + (incl - vsum);
    #pragma unroll
    for (int j = 0; j < 4; ++j) {
        int idx = base + j;
        if (idx < NN) { rowstart[idx] = run; run += v[j]; }
    }
}

// ---------------- CSR fill (no atomics): edat[pos] = {src, bits(RAW w)} ----------------

__global__ __launch_bounds__(256) void k_fill(const int4* __restrict__ src4, const int4* __restrict__ dst4,
                                              const float4* __restrict__ w4, const int* __restrict__ rowstart,
                                              const int4* __restrict__ slot4, int2* __restrict__ edat) {
    int i = blockIdx.x * 256 + threadIdx.x;
    if (i < NE4) {
        int4 s = src4[i]; int4 d = dst4[i]; float4 wv = w4[i]; int4 sl = slot4[i];
        edat[rowstart[d.x] + sl.x] = make_int2(s.x, __float_as_int(wv.x));
        edat[rowstart[d.y] + sl.y] = make_int2(s.y, __float_as_int(wv.y));
        edat[rowstart[d.z] + sl.z] = make_int2(s.z, __float_as_int(wv.z));
        edat[rowstart[d.w] + sl.w] = make_int2(s.w, __float_as_int(wv.w));
    }
}

// ---------------- deg -> dinv (no atomics): deg = 1 + sum_row(w) ----------------

__global__ __launch_bounds__(256) void k_degdinv(const int* __restrict__ rs, const int2* __restrict__ edat,
                                                 float* __restrict__ dinv) {
    int i = blockIdx.x * 256 + threadIdx.x;
    if (i < NN) {
        float dg = 1.0f;  // self-loop weight
        int p1 = rs[i + 1];
        for (int p = rs[i]; p < p1; ++p) dg += __int_as_float(edat[p].y);
        dinv[i] = (dg > 0.0f) ? (1.0f / sqrtf(fmaxf(dg, 1e-12f))) : 0.0f;
    }
}

// ---------------- norm: edat[p].y = bits(dinv[src] * w)  (dinv[dst] applied in k_agg) ----------------

__global__ __launch_bounds__(256) void k_norm(const float* __restrict__ dinv, int2* __restrict__ edat) {
    int p = blockIdx.x * 256 + threadIdx.x;
    if (p < NE) {
        int2 ed = edat[p];
        edat[p].y = __float_as_int(dinv[ed.x] * __int_as_float(ed.y));
    }
}

// ---------------- MFMA GEMM: Hb = bf16( Ab @ W )  (Ab bf16 [NN][128], Wb swizzled) ----------------
// Block 256 = 4 waves, 128 rows. Wave: 32 rows (2 row-frags) x 128 cols (8 col-frags),
// K-loop 4 x 32. Fragment layouts (guide-verified): A row=l&15, k=(l>>4)*8+j;
// B col=l&15, same k; C/D col=l&15, row=(l>>4)*4+reg.

__global__ __launch_bounds__(256) void k_gemm(const unsigned short* __restrict__ Ab,
                                              const unsigned short* __restrict__ Wb,
                                              unsigned short* __restrict__ Hb) {
    int t = threadIdx.x;
    int w = t >> 6, l = t & 63;
    int lr = l & 15, lk = l >> 4;
    int rbase = blockIdx.x * 128 + w * 32;

    f32x4 acc[2][8];
    #pragma unroll
    for (int rt = 0; rt < 2; ++rt)
        #pragma unroll
        for (int ct = 0; ct < 8; ++ct) acc[rt][ct] = (f32x4){0.f, 0.f, 0.f, 0.f};

    int r0 = rbase + lr;      if (r0 > NN - 1) r0 = NN - 1;
    int r1 = rbase + 16 + lr; if (r1 > NN - 1) r1 = NN - 1;
    const unsigned short* a0p = Ab + (size_t)r0 * NC + lk * 8;
    const unsigned short* a1p = Ab + (size_t)r1 * NC + lk * 8;
    const unsigned short* wp  = Wb + (size_t)l * 8;

    #pragma unroll
    for (int ks = 0; ks < 4; ++ks) {
        short8 a0 = *(const short8*)(a0p + ks * 32);
        short8 a1 = *(const short8*)(a1p + ks * 32);
        #pragma unroll
        for (int ct = 0; ct < 8; ++ct) {
            short8 b = *(const short8*)(wp + (size_t)(ks * 8 + ct) * 512);
            acc[0][ct] = __builtin_amdgcn_mfma_f32_16x16x32_bf16(a0, b, acc[0][ct], 0, 0, 0);
            acc[1][ct] = __builtin_amdgcn_mfma_f32_16x16x32_bf16(a1, b, acc[1][ct], 0, 0, 0);
        }
    }

    #pragma unroll
    for (int rt = 0; rt < 2; ++rt) {
        int rowb = rbase + rt * 16 + lk * 4;
        #pragma unroll
        for (int r = 0; r < 4; ++r) {
            int row = rowb + r;
            if (row < NN) {
                unsigned short* hp = Hb + (size_t)row * NC + lr;
                #pragma unroll
                for (int ct = 0; ct < 8; ++ct)
                    hp[ct * 16] = (unsigned short)f2bf(acc[rt][ct][r]);
            }
        }
    }
}

// ---------------- aggregation ----------------
// One 16-lane group owns one node; serial row walk, 4-deep unroll over
// CONSECUTIVE CSR slots. OB=1: write bf16 (Ab, one uint4/lane); OB=0: f32 out.

#define AGG_FMA8(NW, U)                                                                    \
    do {                                                                                   \
        acc0.x = fmaf((NW), BFLO((U).x), acc0.x); acc0.y = fmaf((NW), BFHI((U).x), acc0.y);\
        acc0.z = fmaf((NW), BFLO((U).y), acc0.z); acc0.w = fmaf((NW), BFHI((U).y), acc0.w);\
        acc1.x = fmaf((NW), BFLO((U).z), acc1.x); acc1.y = fmaf((NW), BFHI((U).z), acc1.y);\
        acc1.z = fmaf((NW), BFLO((U).w), acc1.z); acc1.w = fmaf((NW), BFHI((U).w), acc1.w);\
    } while (0)

template <int RELU, int OB>
__global__ __launch_bounds__(256) void k_agg(const unsigned short* __restrict__ Hb, const int* __restrict__ rs,
                                             const int2* __restrict__ edat,
                                             const float* __restrict__ dinv, const float* __restrict__ bias,
                                             void* __restrict__ outv) {
    int node = (blockIdx.x * 256 + threadIdx.x) >> 4;
    int cl   = threadIdx.x & 15;   // owns channels cl*8 .. cl*8+7
    if (node >= NN) return;

    float di = dinv[node];
    float4 acc0, acc1;

    {
        uint4 U = *(const uint4*)(Hb + (size_t)node * NC + cl * 8);
        acc0.x = BFLO(U.x) * di; acc0.y = BFHI(U.x) * di;
        acc0.z = BFLO(U.y) * di; acc0.w = BFHI(U.y) * di;
        acc1.x = BFLO(U.z) * di; acc1.y = BFHI(U.z) * di;
        acc1.z = BFLO(U.w) * di; acc1.w = BFHI(U.w) * di;
    }

    int p0 = rs[node], p1 = rs[node + 1];
    int p = p0;
    for (; p + 3 < p1; p += 4) {
        long long r1 = __builtin_nontemporal_load((const long long*)&edat[p + 0]);
        long long r2 = __builtin_nontemporal_load((const long long*)&edat[p + 1]);
        long long r3 = __builtin_nontemporal_load((const long long*)&edat[p + 2]);
        long long r4 = __builtin_nontemporal_load((const long long*)&edat[p + 3]);
        int   s1 = (int)(r1 & 0xffffffffLL);  float nw1 = __int_as_float((int)(r1 >> 32));
        int   s2 = (int)(r2 & 0xffffffffLL);  float nw2 = __int_as_float((int)(r2 >> 32));
        int   s3 = (int)(r3 & 0xffffffffLL);  float nw3 = __int_as_float((int)(r3 >> 32));
        int   s4 = (int)(r4 & 0xffffffffLL);  float nw4 = __int_as_float((int)(r4 >> 32));
        uint4 U1 = *(const uint4*)(Hb + (size_t)s1 * NC + cl * 8);
        uint4 U2 = *(const uint4*)(Hb + (size_t)s2 * NC + cl * 8);
        uint4 U3 = *(const uint4*)(Hb + (size_t)s3 * NC + cl * 8);
        uint4 U4 = *(const uint4*)(Hb + (size_t)s4 * NC + cl * 8);
        AGG_FMA8(nw1, U1);
        AGG_FMA8(nw2, U2);
        AGG_FMA8(nw3, U3);
        AGG_FMA8(nw4, U4);
    }
    for (; p < p1; ++p) {
        long long r1 = __builtin_nontemporal_load((const long long*)&edat[p]);
        int   s1 = (int)(r1 & 0xffffffffLL);  float nw1 = __int_as_float((int)(r1 >> 32));
        uint4 U1 = *(const uint4*)(Hb + (size_t)s1 * NC + cl * 8);
        AGG_FMA8(nw1, U1);
    }

    const float4* bp = (const float4*)(bias + cl * 8);
    float4 bv0 = bp[0], bv1 = bp[1];
    acc0.x = fmaf(acc0.x, di, bv0.x); acc0.y = fmaf(acc0.y, di, bv0.y);
    acc0.z = fmaf(acc0.z, di, bv0.z); acc0.w = fmaf(acc0.w, di, bv0.w);
    acc1.x = fmaf(acc1.x, di, bv1.x); acc1.y = fmaf(acc1.y, di, bv1.y);
    acc1.z = fmaf(acc1.z, di, bv1.z); acc1.w = fmaf(acc1.w, di, bv1.w);
    if (RELU) {
        acc0.x = fmaxf(acc0.x, 0.f); acc0.y = fmaxf(acc0.y, 0.f);
        acc0.z = fmaxf(acc0.z, 0.f); acc0.w = fmaxf(acc0.w, 0.f);
        acc1.x = fmaxf(acc1.x, 0.f); acc1.y = fmaxf(acc1.y, 0.f);
        acc1.z = fmaxf(acc1.z, 0.f); acc1.w = fmaxf(acc1.w, 0.f);
    }
    if (OB) {
        unsigned short* op = (unsigned short*)outv + (size_t)node * NC + cl * 8;
        uint4 o;
        o.x = f2bf(acc0.x) | (f2bf(acc0.y) << 16);
        o.y = f2bf(acc0.z) | (f2bf(acc0.w) << 16);
        o.z = f2bf(acc1.x) | (f2bf(acc1.y) << 16);
        o.w = f2bf(acc1.z) | (f2bf(acc1.w) << 16);
        *(uint4*)op = o;
    } else {
        float* op = (float*)outv + (size_t)node * NC + cl * 8;
        *(float4*)op       = acc0;
        *(float4*)(op + 4) = acc1;
    }
}

// ---------------- launch ----------------

static inline size_t alignup(size_t x) { return (x + 255) & ~(size_t)255; }

extern "C" void kernel_launch(void* const* d_in, const int* in_sizes, int n_in,
                              void* d_out, int out_size, void* d_ws, size_t ws_size,
                              hipStream_t stream) {
    const float* X  = (const float*)d_in[0];
    const int*   ei = (const int*)d_in[1];          // [2, NE]: row0 = src, row1 = dst
    const float* ew = (const float*)d_in[2];
    const float* W1 = (const float*)d_in[3]; const float* b1 = (const float*)d_in[4];
    const float* W2 = (const float*)d_in[5]; const float* b2 = (const float*)d_in[6];
    const float* W3 = (const float*)d_in[7]; const float* b3 = (const float*)d_in[8];
    float* out = (float*)d_out;

    const int* srcp = ei;
    const int* dstp = ei + NE;

    // workspace carve
    char* w = (char*)d_ws;
    size_t need = 0;
    auto carve = [&](size_t bytes) { char* p = w + need; need += alignup(bytes); return p; };
    float* dinv     = (float*)carve(NN * 4);
    int*   cnt      = (int*)  carve(NN * 4);
    int*   rowstart = (int*)  carve((NN + 1) * 4);
    int*   bsum     = (int*)  carve(NB * 4);
    int*   slot     = (int*)  carve((size_t)NE * 4);
    int2*  edat     = (int2*) carve((size_t)NE * 8);
    unsigned short* Hb  = (unsigned short*)carve((size_t)NN * NC * 2);
    unsigned short* Ab  = (unsigned short*)carve((size_t)NN * NC * 2);
    unsigned short* Xb  = (unsigned short*)carve((size_t)NN * NC * 2);
    unsigned short* Wb1 = (unsigned short*)carve(128 * 128 * 2);
    unsigned short* Wb2 = (unsigned short*)carve(128 * 128 * 2);
    unsigned short* Wb3 = (unsigned short*)carve(128 * 128 * 2);
    if (need > ws_size) return;  // workspace too small -> visible validation failure

    const int gN  = (NN + 255) / 256;
    const int gE  = (NE + 255) / 256;
    const int gE4 = (NE4 + 255) / 256;
    const int gGemm = (NN + 127) / 128;
    const int gAgg  = (NN * 16 + 255) / 256;  // one 16-lane group per node
    const int gW    = (2048 + 255) / 256;

    // CSR build; X->bf16 conversion hidden under the count atomic drain
    k_init<<<gN, 256, 0, stream>>>(cnt);
    k_count<<<gE4, 256, 0, stream>>>((const int4*)dstp, cnt, (int4*)slot,
                                     (const float4*)X, (uint4*)Xb);
    k_wconv<<<gW, 256, 0, stream>>>(W1, Wb1);
    k_wconv<<<gW, 256, 0, stream>>>(W2, Wb2);
    k_wconv<<<gW, 256, 0, stream>>>(W3, Wb3);
    k_scan1<<<NB, 256, 0, stream>>>(cnt, bsum);
    k_scan2<<<1, 64, 0, stream>>>(bsum, rowstart);
    k_scan3<<<NB, 256, 0, stream>>>(cnt, bsum, rowstart);
    k_fill<<<gE4, 256, 0, stream>>>((const int4*)srcp, (const int4*)dstp, (const float4*)ew,
                                    rowstart, (const int4*)slot, edat);
    k_degdinv<<<gN, 256, 0, stream>>>(rowstart, edat, dinv);
    k_norm<<<gE, 256, 0, stream>>>(dinv, edat);

    // layer 1
    k_gemm<<<gGemm, 256, 0, stream>>>(Xb, Wb1, Hb);
    k_agg<1, 1><<<gAgg, 256, 0, stream>>>(Hb, rowstart, edat, dinv, b1, Ab);
    // layer 2
    k_gemm<<<gGemm, 256, 0, stream>>>(Ab, Wb2, Hb);
    k_agg<1, 1><<<gAgg, 256, 0, stream>>>(Hb, rowstart, edat, dinv, b2, Ab);
    // layer 3
    k_gemm<<<gGemm, 256, 0, stream>>>(Ab, Wb3, Hb);
    k_agg<0, 0><<<gAgg, 256, 0, stream>>>(Hb, rowstart, edat, dinv, b3, out);
}

// Round 13
// 390.091 us; speedup vs baseline: 1.3630x; 1.0685x over previous
//
#include <hip/hip_runtime.h>
#include <hip/hip_bf16.h>
#include <cstdint>

#define NN 100000
#define NE 1600000
#define NC 128

constexpr int SCAN_SEG = 1024;
constexpr int NB = (NN + SCAN_SEG - 1) / SCAN_SEG; // 98
constexpr int NE4 = NE / 4;                        // 400000 (== NN*128/32: each count thread converts 32 X elems)

typedef __attribute__((ext_vector_type(8))) short short8;
typedef __attribute__((ext_vector_type(4))) float f32x4;

// ---------------- bf16 helpers ----------------

__device__ __forceinline__ unsigned int f2bf(float f) {
    unsigned int u = __float_as_uint(f);
    u = (u + 0x7fffu + ((u >> 16) & 1u)) >> 16;   // RNE
    return u & 0xffffu;
}
#define BFLO(u) __uint_as_float((u) << 16)
#define BFHI(u) __uint_as_float((u) & 0xffff0000u)

// ---------------- CSR build ----------------

__global__ __launch_bounds__(256) void k_init(int* __restrict__ cnt) {
    int i = blockIdx.x * 256 + threadIdx.x;
    if (i < NN) cnt[i] = 0;
}

// count atomics + slot write, with X->bf16 conversion folded into the
// atomic-latency shadow.
__global__ __launch_bounds__(256) void k_count(const int4* __restrict__ dst4, int* __restrict__ cnt,
                                               int4* __restrict__ slot4,
                                               const float4* __restrict__ X4, uint4* __restrict__ Xb4) {
    int i = blockIdx.x * 256 + threadIdx.x;
    if (i >= NE4) return;
    int4 d = dst4[i];
    int4 s;
    s.x = atomicAdd(&cnt[d.x], 1);
    s.y = atomicAdd(&cnt[d.y], 1);
    s.z = atomicAdd(&cnt[d.z], 1);
    s.w = atomicAdd(&cnt[d.w], 1);
    #pragma unroll
    for (int c = 0; c < 4; ++c) {
        float4 u = X4[(size_t)i * 8 + c * 2];
        float4 v = X4[(size_t)i * 8 + c * 2 + 1];
        uint4 o;
        o.x = f2bf(u.x) | (f2bf(u.y) << 16);
        o.y = f2bf(u.z) | (f2bf(u.w) << 16);
        o.z = f2bf(v.x) | (f2bf(v.y) << 16);
        o.w = f2bf(v.z) | (f2bf(v.w) << 16);
        Xb4[(size_t)i * 4 + c] = o;
    }
    slot4[i] = s;
}

// ---------------- W -> fragment-swizzled bf16 ----------------

__global__ __launch_bounds__(256) void k_wconv(const float* __restrict__ W, unsigned short* __restrict__ Wb) {
    int j = blockIdx.x * 256 + threadIdx.x;
    if (j >= 2048) return;
    int f = j >> 6, l = j & 63;
    int ks = f >> 3, ct = f & 7;
    int kb  = ks * 32 + (l >> 4) * 8;
    int col = ct * 16 + (l & 15);
    uint4 o;
    o.x = f2bf(W[(size_t)(kb + 0) * NC + col]) | (f2bf(W[(size_t)(kb + 1) * NC + col]) << 16);
    o.y = f2bf(W[(size_t)(kb + 2) * NC + col]) | (f2bf(W[(size_t)(kb + 3) * NC + col]) << 16);
    o.z = f2bf(W[(size_t)(kb + 4) * NC + col]) | (f2bf(W[(size_t)(kb + 5) * NC + col]) << 16);
    o.w = f2bf(W[(size_t)(kb + 6) * NC + col]) | (f2bf(W[(size_t)(kb + 7) * NC + col]) << 16);
    *(uint4*)(Wb + (size_t)j * 8) = o;
}

// ---------------- exclusive scan of cnt -> rowstart ----------------

__global__ __launch_bounds__(256) void k_scan1(const int* __restrict__ cnt, int* __restrict__ bsum) {
    __shared__ int sdata[256];
    int b = blockIdx.x, t = threadIdx.x;
    int base = b * SCAN_SEG + t * 4;
    int s = 0;
    #pragma unroll
    for (int j = 0; j < 4; ++j) { int idx = base + j; if (idx < NN) s += cnt[idx]; }
    sdata[t] = s; __syncthreads();
    for (int off = 128; off > 0; off >>= 1) {
        if (t < off) sdata[t] += sdata[t + off];
        __syncthreads();
    }
    if (t == 0) bsum[b] = sdata[0];
}

__global__ void k_scan2(int* __restrict__ bsum, int* __restrict__ rowstart) {
    if (threadIdx.x == 0 && blockIdx.x == 0) {
        int run = 0;
        for (int i = 0; i < NB; ++i) { int v = bsum[i]; bsum[i] = run; run += v; }
        rowstart[NN] = run;  // == NE
    }
}

__global__ __launch_bounds__(256) void k_scan3(const int* __restrict__ cnt, const int* __restrict__ bsum,
                                               int* __restrict__ rowstart) {
    __shared__ int sdata[256];
    int b = blockIdx.x, t = threadIdx.x;
    int base = b * SCAN_SEG + t * 4;
    int v[4]; int vsum = 0;
    #pragma unroll
    for (int j = 0; j < 4; ++j) { int idx = base + j; v[j] = (idx < NN) ? cnt[idx] : 0; vsum += v[j]; }
    sdata[t] = vsum; __syncthreads();
    int incl = vsum;
    for (int off = 1; off < 256; off <<= 1) {
        int add = (t >= off) ? sdata[t - off] : 0;
        __syncthreads();
        incl += add;
        sdata[t] = incl;
        __syncthreads();
    }
    int run = bsum[b] + (incl - vsum);
    #pragma unroll
    for (int j = 0; j < 4; ++j) {
        int idx = base + j;
        if (idx < NN) { rowstart[idx] = run; run += v[j]; }
    }
}

// ---------------- CSR fill (no atomics): edat[pos] = {src, bits(RAW w)} ----------------

__global__ __launch_bounds__(256) void k_fill(const int4* __restrict__ src4, const int4* __restrict__ dst4,
                                              const float4* __restrict__ w4, const int* __restrict__ rowstart,
                                              const int4* __restrict__ slot4, int2* __restrict__ edat) {
    int i = blockIdx.x * 256 + threadIdx.x;
    if (i < NE4) {
        int4 s = src4[i]; int4 d = dst4[i]; float4 wv = w4[i]; int4 sl = slot4[i];
        edat[rowstart[d.x] + sl.x] = make_int2(s.x, __float_as_int(wv.x));
        edat[rowstart[d.y] + sl.y] = make_int2(s.y, __float_as_int(wv.y));
        edat[rowstart[d.z] + sl.z] = make_int2(s.z, __float_as_int(wv.z));
        edat[rowstart[d.w] + sl.w] = make_int2(s.w, __float_as_int(wv.w));
    }
}

// ---------------- deg -> dinv (no atomics): deg = 1 + sum_row(w) ----------------

__global__ __launch_bounds__(256) void k_degdinv(const int* __restrict__ rs, const int2* __restrict__ edat,
                                                 float* __restrict__ dinv) {
    int i = blockIdx.x * 256 + threadIdx.x;
    if (i < NN) {
        float dg = 1.0f;  // self-loop weight
        int p1 = rs[i + 1];
        for (int p = rs[i]; p < p1; ++p) dg += __int_as_float(edat[p].y);
        dinv[i] = (dg > 0.0f) ? (1.0f / sqrtf(fmaxf(dg, 1e-12f))) : 0.0f;
    }
}

// ---------------- MFMA GEMM: Hb = bf16( Ab @ W ) ----------------

__global__ __launch_bounds__(256) void k_gemm(const unsigned short* __restrict__ Ab,
                                              const unsigned short* __restrict__ Wb,
                                              unsigned short* __restrict__ Hb) {
    int t = threadIdx.x;
    int w = t >> 6, l = t & 63;
    int lr = l & 15, lk = l >> 4;
    int rbase = blockIdx.x * 128 + w * 32;

    f32x4 acc[2][8];
    #pragma unroll
    for (int rt = 0; rt < 2; ++rt)
        #pragma unroll
        for (int ct = 0; ct < 8; ++ct) acc[rt][ct] = (f32x4){0.f, 0.f, 0.f, 0.f};

    int r0 = rbase + lr;      if (r0 > NN - 1) r0 = NN - 1;
    int r1 = rbase + 16 + lr; if (r1 > NN - 1) r1 = NN - 1;
    const unsigned short* a0p = Ab + (size_t)r0 * NC + lk * 8;
    const unsigned short* a1p = Ab + (size_t)r1 * NC + lk * 8;
    const unsigned short* wp  = Wb + (size_t)l * 8;

    #pragma unroll
    for (int ks = 0; ks < 4; ++ks) {
        short8 a0 = *(const short8*)(a0p + ks * 32);
        short8 a1 = *(const short8*)(a1p + ks * 32);
        #pragma unroll
        for (int ct = 0; ct < 8; ++ct) {
            short8 b = *(const short8*)(wp + (size_t)(ks * 8 + ct) * 512);
            acc[0][ct] = __builtin_amdgcn_mfma_f32_16x16x32_bf16(a0, b, acc[0][ct], 0, 0, 0);
            acc[1][ct] = __builtin_amdgcn_mfma_f32_16x16x32_bf16(a1, b, acc[1][ct], 0, 0, 0);
        }
    }

    #pragma unroll
    for (int rt = 0; rt < 2; ++rt) {
        int rowb = rbase + rt * 16 + lk * 4;
        #pragma unroll
        for (int r = 0; r < 4; ++r) {
            int row = rowb + r;
            if (row < NN) {
                unsigned short* hp = Hb + (size_t)row * NC + lr;
                #pragma unroll
                for (int ct = 0; ct < 8; ++ct)
                    hp[ct * 16] = (unsigned short)f2bf(acc[rt][ct][r]);
            }
        }
    }
}

// ---------------- aggregation ----------------
// One 16-lane group owns one node; serial row walk, 8-deep + 4-deep + scalar
// unroll over CONSECUTIVE CSR slots (32 H-lines in flight per wave).
// NORMW=1 (layer 1): edat.y holds RAW w; compute nw=dinv[src]*w in-flight and
// write it back (lane 0) for layers 2-3 — bitwise-identical to the old k_norm.
// OB=1: write bf16 Ab; OB=0: f32 out.

#define AGG_FMA8(NW, U)                                                                    \
    do {                                                                                   \
        acc0.x = fmaf((NW), BFLO((U).x), acc0.x); acc0.y = fmaf((NW), BFHI((U).x), acc0.y);\
        acc0.z = fmaf((NW), BFLO((U).y), acc0.z); acc0.w = fmaf((NW), BFHI((U).y), acc0.w);\
        acc1.x = fmaf((NW), BFLO((U).z), acc1.x); acc1.y = fmaf((NW), BFHI((U).z), acc1.y);\
        acc1.z = fmaf((NW), BFLO((U).w), acc1.z); acc1.w = fmaf((NW), BFHI((U).w), acc1.w);\
    } while (0)

template <int RELU, int OB, int NORMW>
__global__ __launch_bounds__(256) void k_agg(const unsigned short* __restrict__ Hb, const int* __restrict__ rs,
                                             int2* __restrict__ edat,
                                             const float* __restrict__ dinv, const float* __restrict__ bias,
                                             void* __restrict__ outv) {
    int node = (blockIdx.x * 256 + threadIdx.x) >> 4;
    int cl   = threadIdx.x & 15;   // owns channels cl*8 .. cl*8+7
    if (node >= NN) return;

    float di = dinv[node];
    float4 acc0, acc1;

    {
        uint4 U = *(const uint4*)(Hb + (size_t)node * NC + cl * 8);
        acc0.x = BFLO(U.x) * di; acc0.y = BFHI(U.x) * di;
        acc0.z = BFLO(U.y) * di; acc0.w = BFHI(U.y) * di;
        acc1.x = BFLO(U.z) * di; acc1.y = BFHI(U.z) * di;
        acc1.z = BFLO(U.w) * di; acc1.w = BFHI(U.w) * di;
    }

    int p0 = rs[node], p1 = rs[node + 1];
    int p = p0;
    for (; p + 7 < p1; p += 8) {
        int2 e0 = edat[p+0], e1 = edat[p+1], e2 = edat[p+2], e3 = edat[p+3];
        int2 e4 = edat[p+4], e5 = edat[p+5], e6 = edat[p+6], e7 = edat[p+7];
        float nw0, nw1, nw2, nw3, nw4, nw5, nw6, nw7;
        if (NORMW) {
            nw0 = dinv[e0.x] * __int_as_float(e0.y);
            nw1 = dinv[e1.x] * __int_as_float(e1.y);
            nw2 = dinv[e2.x] * __int_as_float(e2.y);
            nw3 = dinv[e3.x] * __int_as_float(e3.y);
            nw4 = dinv[e4.x] * __int_as_float(e4.y);
            nw5 = dinv[e5.x] * __int_as_float(e5.y);
            nw6 = dinv[e6.x] * __int_as_float(e6.y);
            nw7 = dinv[e7.x] * __int_as_float(e7.y);
            if (cl == 0) {
                edat[p+0].y = __float_as_int(nw0); edat[p+1].y = __float_as_int(nw1);
                edat[p+2].y = __float_as_int(nw2); edat[p+3].y = __float_as_int(nw3);
                edat[p+4].y = __float_as_int(nw4); edat[p+5].y = __float_as_int(nw5);
                edat[p+6].y = __float_as_int(nw6); edat[p+7].y = __float_as_int(nw7);
            }
        } else {
            nw0 = __int_as_float(e0.y); nw1 = __int_as_float(e1.y);
            nw2 = __int_as_float(e2.y); nw3 = __int_as_float(e3.y);
            nw4 = __int_as_float(e4.y); nw5 = __int_as_float(e5.y);
            nw6 = __int_as_float(e6.y); nw7 = __int_as_float(e7.y);
        }
        uint4 U0 = *(const uint4*)(Hb + (size_t)e0.x * NC + cl * 8);
        uint4 U1 = *(const uint4*)(Hb + (size_t)e1.x * NC + cl * 8);
        uint4 U2 = *(const uint4*)(Hb + (size_t)e2.x * NC + cl * 8);
        uint4 U3 = *(const uint4*)(Hb + (size_t)e3.x * NC + cl * 8);
        uint4 U4 = *(const uint4*)(Hb + (size_t)e4.x * NC + cl * 8);
        uint4 U5 = *(const uint4*)(Hb + (size_t)e5.x * NC + cl * 8);
        uint4 U6 = *(const uint4*)(Hb + (size_t)e6.x * NC + cl * 8);
        uint4 U7 = *(const uint4*)(Hb + (size_t)e7.x * NC + cl * 8);
        AGG_FMA8(nw0, U0); AGG_FMA8(nw1, U1); AGG_FMA8(nw2, U2); AGG_FMA8(nw3, U3);
        AGG_FMA8(nw4, U4); AGG_FMA8(nw5, U5); AGG_FMA8(nw6, U6); AGG_FMA8(nw7, U7);
    }
    for (; p + 3 < p1; p += 4) {
        int2 e0 = edat[p+0], e1 = edat[p+1], e2 = edat[p+2], e3 = edat[p+3];
        float nw0, nw1, nw2, nw3;
        if (NORMW) {
            nw0 = dinv[e0.x] * __int_as_float(e0.y);
            nw1 = dinv[e1.x] * __int_as_float(e1.y);
            nw2 = dinv[e2.x] * __int_as_float(e2.y);
            nw3 = dinv[e3.x] * __int_as_float(e3.y);
            if (cl == 0) {
                edat[p+0].y = __float_as_int(nw0); edat[p+1].y = __float_as_int(nw1);
                edat[p+2].y = __float_as_int(nw2); edat[p+3].y = __float_as_int(nw3);
            }
        } else {
            nw0 = __int_as_float(e0.y); nw1 = __int_as_float(e1.y);
            nw2 = __int_as_float(e2.y); nw3 = __int_as_float(e3.y);
        }
        uint4 U0 = *(const uint4*)(Hb + (size_t)e0.x * NC + cl * 8);
        uint4 U1 = *(const uint4*)(Hb + (size_t)e1.x * NC + cl * 8);
        uint4 U2 = *(const uint4*)(Hb + (size_t)e2.x * NC + cl * 8);
        uint4 U3 = *(const uint4*)(Hb + (size_t)e3.x * NC + cl * 8);
        AGG_FMA8(nw0, U0); AGG_FMA8(nw1, U1); AGG_FMA8(nw2, U2); AGG_FMA8(nw3, U3);
    }
    for (; p < p1; ++p) {
        int2 e0 = edat[p];
        float nw0;
        if (NORMW) {
            nw0 = dinv[e0.x] * __int_as_float(e0.y);
            if (cl == 0) edat[p].y = __float_as_int(nw0);
        } else {
            nw0 = __int_as_float(e0.y);
        }
        uint4 U0 = *(const uint4*)(Hb + (size_t)e0.x * NC + cl * 8);
        AGG_FMA8(nw0, U0);
    }

    const float4* bp = (const float4*)(bias + cl * 8);
    float4 bv0 = bp[0], bv1 = bp[1];
    acc0.x = fmaf(acc0.x, di, bv0.x); acc0.y = fmaf(acc0.y, di, bv0.y);
    acc0.z = fmaf(acc0.z, di, bv0.z); acc0.w = fmaf(acc0.w, di, bv0.w);
    acc1.x = fmaf(acc1.x, di, bv1.x); acc1.y = fmaf(acc1.y, di, bv1.y);
    acc1.z = fmaf(acc1.z, di, bv1.z); acc1.w = fmaf(acc1.w, di, bv1.w);
    if (RELU) {
        acc0.x = fmaxf(acc0.x, 0.f); acc0.y = fmaxf(acc0.y, 0.f);
        acc0.z = fmaxf(acc0.z, 0.f); acc0.w = fmaxf(acc0.w, 0.f);
        acc1.x = fmaxf(acc1.x, 0.f); acc1.y = fmaxf(acc1.y, 0.f);
        acc1.z = fmaxf(acc1.z, 0.f); acc1.w = fmaxf(acc1.w, 0.f);
    }
    if (OB) {
        unsigned short* op = (unsigned short*)outv + (size_t)node * NC + cl * 8;
        uint4 o;
        o.x = f2bf(acc0.x) | (f2bf(acc0.y) << 16);
        o.y = f2bf(acc0.z) | (f2bf(acc0.w) << 16);
        o.z = f2bf(acc1.x) | (f2bf(acc1.y) << 16);
        o.w = f2bf(acc1.z) | (f2bf(acc1.w) << 16);
        *(uint4*)op = o;
    } else {
        float* op = (float*)outv + (size_t)node * NC + cl * 8;
        *(float4*)op       = acc0;
        *(float4*)(op + 4) = acc1;
    }
}

// ---------------- launch ----------------

static inline size_t alignup(size_t x) { return (x + 255) & ~(size_t)255; }

extern "C" void kernel_launch(void* const* d_in, const int* in_sizes, int n_in,
                              void* d_out, int out_size, void* d_ws, size_t ws_size,
                              hipStream_t stream) {
    const float* X  = (const float*)d_in[0];
    const int*   ei = (const int*)d_in[1];          // [2, NE]: row0 = src, row1 = dst
    const float* ew = (const float*)d_in[2];
    const float* W1 = (const float*)d_in[3]; const float* b1 = (const float*)d_in[4];
    const float* W2 = (const float*)d_in[5]; const float* b2 = (const float*)d_in[6];
    const float* W3 = (const float*)d_in[7]; const float* b3 = (const float*)d_in[8];
    float* out = (float*)d_out;

    const int* srcp = ei;
    const int* dstp = ei + NE;

    // workspace carve
    char* w = (char*)d_ws;
    size_t need = 0;
    auto carve = [&](size_t bytes) { char* p = w + need; need += alignup(bytes); return p; };
    float* dinv     = (float*)carve(NN * 4);
    int*   cnt      = (int*)  carve(NN * 4);
    int*   rowstart = (int*)  carve((NN + 1) * 4);
    int*   bsum     = (int*)  carve(NB * 4);
    int*   slot     = (int*)  carve((size_t)NE * 4);
    int2*  edat     = (int2*) carve((size_t)NE * 8);
    unsigned short* Hb  = (unsigned short*)carve((size_t)NN * NC * 2);
    unsigned short* Ab  = (unsigned short*)carve((size_t)NN * NC * 2);
    unsigned short* Xb  = (unsigned short*)carve((size_t)NN * NC * 2);
    unsigned short* Wb1 = (unsigned short*)carve(128 * 128 * 2);
    unsigned short* Wb2 = (unsigned short*)carve(128 * 128 * 2);
    unsigned short* Wb3 = (unsigned short*)carve(128 * 128 * 2);
    if (need > ws_size) return;  // workspace too small -> visible validation failure

    const int gN  = (NN + 255) / 256;
    const int gE4 = (NE4 + 255) / 256;
    const int gGemm = (NN + 127) / 128;
    const int gAgg  = (NN * 16 + 255) / 256;  // one 16-lane group per node
    const int gW    = (2048 + 255) / 256;

    // CSR build; X->bf16 conversion hidden under the count atomic drain
    k_init<<<gN, 256, 0, stream>>>(cnt);
    k_count<<<gE4, 256, 0, stream>>>((const int4*)dstp, cnt, (int4*)slot,
                                     (const float4*)X, (uint4*)Xb);
    k_wconv<<<gW, 256, 0, stream>>>(W1, Wb1);
    k_wconv<<<gW, 256, 0, stream>>>(W2, Wb2);
    k_wconv<<<gW, 256, 0, stream>>>(W3, Wb3);
    k_scan1<<<NB, 256, 0, stream>>>(cnt, bsum);
    k_scan2<<<1, 64, 0, stream>>>(bsum, rowstart);
    k_scan3<<<NB, 256, 0, stream>>>(cnt, bsum, rowstart);
    k_fill<<<gE4, 256, 0, stream>>>((const int4*)srcp, (const int4*)dstp, (const float4*)ew,
                                    rowstart, (const int4*)slot, edat);
    k_degdinv<<<gN, 256, 0, stream>>>(rowstart, edat, dinv);

    // layer 1 (norm fold: computes nw=dinv[src]*w in-flight, writes back for layers 2-3)
    k_gemm<<<gGemm, 256, 0, stream>>>(Xb, Wb1, Hb);
    k_agg<1, 1, 1><<<gAgg, 256, 0, stream>>>(Hb, rowstart, edat, dinv, b1, Ab);
    // layer 2
    k_gemm<<<gGemm, 256, 0, stream>>>(Ab, Wb2, Hb);
    k_agg<1, 1, 0><<<gAgg, 256, 0, stream>>>(Hb, rowstart, edat, dinv, b2, Ab);
    // layer 3
    k_gemm<<<gGemm, 256, 0, stream>>>(Ab, Wb3, Hb);
    k_agg<0, 0, 0><<<gAgg, 256, 0, stream>>>(Hb, rowstart, edat, dinv, b3, out);
}

// Round 14
// 387.561 us; speedup vs baseline: 1.3718x; 1.0065x over previous
//
#include <hip/hip_runtime.h>
#include <hip/hip_bf16.h>
#include <cstdint>

#define NN 100000
#define NE 1600000
#define NC 128

constexpr int SCAN_SEG = 1024;
constexpr int NB = (NN + SCAN_SEG - 1) / SCAN_SEG; // 98
constexpr int NE4 = NE / 4;                        // 400000
constexpr int NCHUNK = (NN + 31) / 32;             // 3125 32-node chunks
constexpr int GAGG = ((NCHUNK + 3) / 4) * 8;       // 6256 blocks: b%8 -> XCD; half=(b%8)>>2

typedef __attribute__((ext_vector_type(8))) short short8;
typedef __attribute__((ext_vector_type(4))) float f32x4;

// ---------------- bf16 helpers ----------------

__device__ __forceinline__ unsigned int f2bf(float f) {
    unsigned int u = __float_as_uint(f);
    u = (u + 0x7fffu + ((u >> 16) & 1u)) >> 16;   // RNE
    return u & 0xffffu;
}
#define BFLO(u) __uint_as_float((u) << 16)
#define BFHI(u) __uint_as_float((u) & 0xffff0000u)

// ---------------- CSR build ----------------

__global__ __launch_bounds__(256) void k_init(int* __restrict__ cnt) {
    int i = blockIdx.x * 256 + threadIdx.x;
    if (i < NN) cnt[i] = 0;
}

// count atomics + slot write, with X->bf16 conversion folded into the
// atomic-latency shadow.
__global__ __launch_bounds__(256) void k_count(const int4* __restrict__ dst4, int* __restrict__ cnt,
                                               int4* __restrict__ slot4,
                                               const float4* __restrict__ X4, uint4* __restrict__ Xb4) {
    int i = blockIdx.x * 256 + threadIdx.x;
    if (i >= NE4) return;
    int4 d = dst4[i];
    int4 s;
    s.x = atomicAdd(&cnt[d.x], 1);
    s.y = atomicAdd(&cnt[d.y], 1);
    s.z = atomicAdd(&cnt[d.z], 1);
    s.w = atomicAdd(&cnt[d.w], 1);
    #pragma unroll
    for (int c = 0; c < 4; ++c) {
        float4 u = X4[(size_t)i * 8 + c * 2];
        float4 v = X4[(size_t)i * 8 + c * 2 + 1];
        uint4 o;
        o.x = f2bf(u.x) | (f2bf(u.y) << 16);
        o.y = f2bf(u.z) | (f2bf(u.w) << 16);
        o.z = f2bf(v.x) | (f2bf(v.y) << 16);
        o.w = f2bf(v.z) | (f2bf(v.w) << 16);
        Xb4[(size_t)i * 4 + c] = o;
    }
    slot4[i] = s;
}

// ---------------- W -> fragment-swizzled bf16 ----------------

__global__ __launch_bounds__(256) void k_wconv(const float* __restrict__ W, unsigned short* __restrict__ Wb) {
    int j = blockIdx.x * 256 + threadIdx.x;
    if (j >= 2048) return;
    int f = j >> 6, l = j & 63;
    int ks = f >> 3, ct = f & 7;
    int kb  = ks * 32 + (l >> 4) * 8;
    int col = ct * 16 + (l & 15);
    uint4 o;
    o.x = f2bf(W[(size_t)(kb + 0) * NC + col]) | (f2bf(W[(size_t)(kb + 1) * NC + col]) << 16);
    o.y = f2bf(W[(size_t)(kb + 2) * NC + col]) | (f2bf(W[(size_t)(kb + 3) * NC + col]) << 16);
    o.z = f2bf(W[(size_t)(kb + 4) * NC + col]) | (f2bf(W[(size_t)(kb + 5) * NC + col]) << 16);
    o.w = f2bf(W[(size_t)(kb + 6) * NC + col]) | (f2bf(W[(size_t)(kb + 7) * NC + col]) << 16);
    *(uint4*)(Wb + (size_t)j * 8) = o;
}

// ---------------- exclusive scan of cnt -> rowstart ----------------

__global__ __launch_bounds__(256) void k_scan1(const int* __restrict__ cnt, int* __restrict__ bsum) {
    __shared__ int sdata[256];
    int b = blockIdx.x, t = threadIdx.x;
    int base = b * SCAN_SEG + t * 4;
    int s = 0;
    #pragma unroll
    for (int j = 0; j < 4; ++j) { int idx = base + j; if (idx < NN) s += cnt[idx]; }
    sdata[t] = s; __syncthreads();
    for (int off = 128; off > 0; off >>= 1) {
        if (t < off) sdata[t] += sdata[t + off];
        __syncthreads();
    }
    if (t == 0) bsum[b] = sdata[0];
}

__global__ void k_scan2(int* __restrict__ bsum, int* __restrict__ rowstart) {
    if (threadIdx.x == 0 && blockIdx.x == 0) {
        int run = 0;
        for (int i = 0; i < NB; ++i) { int v = bsum[i]; bsum[i] = run; run += v; }
        rowstart[NN] = run;  // == NE
    }
}

__global__ __launch_bounds__(256) void k_scan3(const int* __restrict__ cnt, const int* __restrict__ bsum,
                                               int* __restrict__ rowstart) {
    __shared__ int sdata[256];
    int b = blockIdx.x, t = threadIdx.x;
    int base = b * SCAN_SEG + t * 4;
    int v[4]; int vsum = 0;
    #pragma unroll
    for (int j = 0; j < 4; ++j) { int idx = base + j; v[j] = (idx < NN) ? cnt[idx] : 0; vsum += v[j]; }
    sdata[t] = vsum; __syncthreads();
    int incl = vsum;
    for (int off = 1; off < 256; off <<= 1) {
        int add = (t >= off) ? sdata[t - off] : 0;
        __syncthreads();
        incl += add;
        sdata[t] = incl;
        __syncthreads();
    }
    int run = bsum[b] + (incl - vsum);
    #pragma unroll
    for (int j = 0; j < 4; ++j) {
        int idx = base + j;
        if (idx < NN) { rowstart[idx] = run; run += v[j]; }
    }
}

// ---------------- CSR fill (no atomics): edat[pos] = {src, bits(RAW w)} ----------------

__global__ __launch_bounds__(256) void k_fill(const int4* __restrict__ src4, const int4* __restrict__ dst4,
                                              const float4* __restrict__ w4, const int* __restrict__ rowstart,
                                              const int4* __restrict__ slot4, int2* __restrict__ edat) {
    int i = blockIdx.x * 256 + threadIdx.x;
    if (i < NE4) {
        int4 s = src4[i]; int4 d = dst4[i]; float4 wv = w4[i]; int4 sl = slot4[i];
        edat[rowstart[d.x] + sl.x] = make_int2(s.x, __float_as_int(wv.x));
        edat[rowstart[d.y] + sl.y] = make_int2(s.y, __float_as_int(wv.y));
        edat[rowstart[d.z] + sl.z] = make_int2(s.z, __float_as_int(wv.z));
        edat[rowstart[d.w] + sl.w] = make_int2(s.w, __float_as_int(wv.w));
    }
}

// ---------------- deg -> dinv (no atomics): deg = 1 + sum_row(w) ----------------

__global__ __launch_bounds__(256) void k_degdinv(const int* __restrict__ rs, const int2* __restrict__ edat,
                                                 float* __restrict__ dinv) {
    int i = blockIdx.x * 256 + threadIdx.x;
    if (i < NN) {
        float dg = 1.0f;  // self-loop weight
        int p1 = rs[i + 1];
        for (int p = rs[i]; p < p1; ++p) dg += __int_as_float(edat[p].y);
        dinv[i] = (dg > 0.0f) ? (1.0f / sqrtf(fmaxf(dg, 1e-12f))) : 0.0f;
    }
}

// ---------------- norm: edat[p].y = bits(dinv[src] * w)  (dinv[dst] applied in k_agg) ----------------

__global__ __launch_bounds__(256) void k_norm(const float* __restrict__ dinv, int2* __restrict__ edat) {
    int p = blockIdx.x * 256 + threadIdx.x;
    if (p < NE) {
        int2 ed = edat[p];
        edat[p].y = __float_as_int(dinv[ed.x] * __int_as_float(ed.y));
    }
}

// ---------------- MFMA GEMM: Hb = bf16( Ab @ W ) ----------------

__global__ __launch_bounds__(256) void k_gemm(const unsigned short* __restrict__ Ab,
                                              const unsigned short* __restrict__ Wb,
                                              unsigned short* __restrict__ Hb) {
    int t = threadIdx.x;
    int w = t >> 6, l = t & 63;
    int lr = l & 15, lk = l >> 4;
    int rbase = blockIdx.x * 128 + w * 32;

    f32x4 acc[2][8];
    #pragma unroll
    for (int rt = 0; rt < 2; ++rt)
        #pragma unroll
        for (int ct = 0; ct < 8; ++ct) acc[rt][ct] = (f32x4){0.f, 0.f, 0.f, 0.f};

    int r0 = rbase + lr;      if (r0 > NN - 1) r0 = NN - 1;
    int r1 = rbase + 16 + lr; if (r1 > NN - 1) r1 = NN - 1;
    const unsigned short* a0p = Ab + (size_t)r0 * NC + lk * 8;
    const unsigned short* a1p = Ab + (size_t)r1 * NC + lk * 8;
    const unsigned short* wp  = Wb + (size_t)l * 8;

    #pragma unroll
    for (int ks = 0; ks < 4; ++ks) {
        short8 a0 = *(const short8*)(a0p + ks * 32);
        short8 a1 = *(const short8*)(a1p + ks * 32);
        #pragma unroll
        for (int ct = 0; ct < 8; ++ct) {
            short8 b = *(const short8*)(wp + (size_t)(ks * 8 + ct) * 512);
            acc[0][ct] = __builtin_amdgcn_mfma_f32_16x16x32_bf16(a0, b, acc[0][ct], 0, 0, 0);
            acc[1][ct] = __builtin_amdgcn_mfma_f32_16x16x32_bf16(a1, b, acc[1][ct], 0, 0, 0);
        }
    }

    #pragma unroll
    for (int rt = 0; rt < 2; ++rt) {
        int rowb = rbase + rt * 16 + lk * 4;
        #pragma unroll
        for (int r = 0; r < 4; ++r) {
            int row = rowb + r;
            if (row < NN) {
                unsigned short* hp = Hb + (size_t)row * NC + lr;
                #pragma unroll
                for (int ct = 0; ct < 8; ++ct)
                    hp[ct * 16] = (unsigned short)f2bf(acc[rt][ct][r]);
            }
        }
    }
}

// ---------------- aggregation: channel-half XCD split ----------------
// Block b: half h=(b%8)>>2 (-> XCDs 0-3 or 4-7 under round-robin blockIdx->XCD),
// 32-node chunk = (b>>3)*4 + (b&3). 8-lane group owns one node's 64-channel
// half; per edge the group reads ONE 128 B line (8 x uint4). Per-XCD compulsory
// fetch halves (12.8 MB vs 25.6). 8-deep unroll = 8 lines in flight per group.
// out[d] = dinv[d]*(sum nrm'*Hb[s] + dinv[d]*Hb[d]) + b. OB=1: bf16; OB=0: f32.

#define AGG_FMA8(NW, U)                                                                    \
    do {                                                                                   \
        acc0.x = fmaf((NW), BFLO((U).x), acc0.x); acc0.y = fmaf((NW), BFHI((U).x), acc0.y);\
        acc0.z = fmaf((NW), BFLO((U).y), acc0.z); acc0.w = fmaf((NW), BFHI((U).y), acc0.w);\
        acc1.x = fmaf((NW), BFLO((U).z), acc1.x); acc1.y = fmaf((NW), BFHI((U).z), acc1.y);\
        acc1.z = fmaf((NW), BFLO((U).w), acc1.z); acc1.w = fmaf((NW), BFHI((U).w), acc1.w);\
    } while (0)

template <int RELU, int OB>
__global__ __launch_bounds__(256) void k_agg(const unsigned short* __restrict__ Hb, const int* __restrict__ rs,
                                             const int2* __restrict__ edat,
                                             const float* __restrict__ dinv, const float* __restrict__ bias,
                                             void* __restrict__ outv) {
    int b = blockIdx.x;
    int h     = (b & 7) >> 2;             // channel half 0/1
    int chunk = (b >> 3) * 4 + (b & 3);   // 32-node chunk
    if (chunk >= NCHUNK) return;
    int grp  = threadIdx.x >> 3;          // 0..31: node within chunk
    int cl   = threadIdx.x & 7;           // owns channels h*64 + cl*8 .. +7
    int node = chunk * 32 + grp;
    if (node >= NN) return;
    int cb = h * 64 + cl * 8;

    float di = dinv[node];
    float4 acc0, acc1;

    {
        uint4 U = *(const uint4*)(Hb + (size_t)node * NC + cb);
        acc0.x = BFLO(U.x) * di; acc0.y = BFHI(U.x) * di;
        acc0.z = BFLO(U.y) * di; acc0.w = BFHI(U.y) * di;
        acc1.x = BFLO(U.z) * di; acc1.y = BFHI(U.z) * di;
        acc1.z = BFLO(U.w) * di; acc1.w = BFHI(U.w) * di;
    }

    int p0 = rs[node], p1 = rs[node + 1];
    int p = p0;
    for (; p + 7 < p1; p += 8) {
        int2 e0 = edat[p+0], e1 = edat[p+1], e2 = edat[p+2], e3 = edat[p+3];
        int2 e4 = edat[p+4], e5 = edat[p+5], e6 = edat[p+6], e7 = edat[p+7];
        uint4 U0 = *(const uint4*)(Hb + (size_t)e0.x * NC + cb);
        uint4 U1 = *(const uint4*)(Hb + (size_t)e1.x * NC + cb);
        uint4 U2 = *(const uint4*)(Hb + (size_t)e2.x * NC + cb);
        uint4 U3 = *(const uint4*)(Hb + (size_t)e3.x * NC + cb);
        uint4 U4 = *(const uint4*)(Hb + (size_t)e4.x * NC + cb);
        uint4 U5 = *(const uint4*)(Hb + (size_t)e5.x * NC + cb);
        uint4 U6 = *(const uint4*)(Hb + (size_t)e6.x * NC + cb);
        uint4 U7 = *(const uint4*)(Hb + (size_t)e7.x * NC + cb);
        AGG_FMA8(__int_as_float(e0.y), U0); AGG_FMA8(__int_as_float(e1.y), U1);
        AGG_FMA8(__int_as_float(e2.y), U2); AGG_FMA8(__int_as_float(e3.y), U3);
        AGG_FMA8(__int_as_float(e4.y), U4); AGG_FMA8(__int_as_float(e5.y), U5);
        AGG_FMA8(__int_as_float(e6.y), U6); AGG_FMA8(__int_as_float(e7.y), U7);
    }
    for (; p + 3 < p1; p += 4) {
        int2 e0 = edat[p+0], e1 = edat[p+1], e2 = edat[p+2], e3 = edat[p+3];
        uint4 U0 = *(const uint4*)(Hb + (size_t)e0.x * NC + cb);
        uint4 U1 = *(const uint4*)(Hb + (size_t)e1.x * NC + cb);
        uint4 U2 = *(const uint4*)(Hb + (size_t)e2.x * NC + cb);
        uint4 U3 = *(const uint4*)(Hb + (size_t)e3.x * NC + cb);
        AGG_FMA8(__int_as_float(e0.y), U0); AGG_FMA8(__int_as_float(e1.y), U1);
        AGG_FMA8(__int_as_float(e2.y), U2); AGG_FMA8(__int_as_float(e3.y), U3);
    }
    for (; p < p1; ++p) {
        int2 e0 = edat[p];
        uint4 U0 = *(const uint4*)(Hb + (size_t)e0.x * NC + cb);
        AGG_FMA8(__int_as_float(e0.y), U0);
    }

    const float4* bp = (const float4*)(bias + cb);
    float4 bv0 = bp[0], bv1 = bp[1];
    acc0.x = fmaf(acc0.x, di, bv0.x); acc0.y = fmaf(acc0.y, di, bv0.y);
    acc0.z = fmaf(acc0.z, di, bv0.z); acc0.w = fmaf(acc0.w, di, bv0.w);
    acc1.x = fmaf(acc1.x, di, bv1.x); acc1.y = fmaf(acc1.y, di, bv1.y);
    acc1.z = fmaf(acc1.z, di, bv1.z); acc1.w = fmaf(acc1.w, di, bv1.w);
    if (RELU) {
        acc0.x = fmaxf(acc0.x, 0.f); acc0.y = fmaxf(acc0.y, 0.f);
        acc0.z = fmaxf(acc0.z, 0.f); acc0.w = fmaxf(acc0.w, 0.f);
        acc1.x = fmaxf(acc1.x, 0.f); acc1.y = fmaxf(acc1.y, 0.f);
        acc1.z = fmaxf(acc1.z, 0.f); acc1.w = fmaxf(acc1.w, 0.f);
    }
    if (OB) {
        unsigned short* op = (unsigned short*)outv + (size_t)node * NC + cb;
        uint4 o;
        o.x = f2bf(acc0.x) | (f2bf(acc0.y) << 16);
        o.y = f2bf(acc0.z) | (f2bf(acc0.w) << 16);
        o.z = f2bf(acc1.x) | (f2bf(acc1.y) << 16);
        o.w = f2bf(acc1.z) | (f2bf(acc1.w) << 16);
        *(uint4*)op = o;
    } else {
        float* op = (float*)outv + (size_t)node * NC + cb;
        *(float4*)op       = acc0;
        *(float4*)(op + 4) = acc1;
    }
}

// ---------------- launch ----------------

static inline size_t alignup(size_t x) { return (x + 255) & ~(size_t)255; }

extern "C" void kernel_launch(void* const* d_in, const int* in_sizes, int n_in,
                              void* d_out, int out_size, void* d_ws, size_t ws_size,
                              hipStream_t stream) {
    const float* X  = (const float*)d_in[0];
    const int*   ei = (const int*)d_in[1];          // [2, NE]: row0 = src, row1 = dst
    const float* ew = (const float*)d_in[2];
    const float* W1 = (const float*)d_in[3]; const float* b1 = (const float*)d_in[4];
    const float* W2 = (const float*)d_in[5]; const float* b2 = (const float*)d_in[6];
    const float* W3 = (const float*)d_in[7]; const float* b3 = (const float*)d_in[8];
    float* out = (float*)d_out;

    const int* srcp = ei;
    const int* dstp = ei + NE;

    // workspace carve
    char* w = (char*)d_ws;
    size_t need = 0;
    auto carve = [&](size_t bytes) { char* p = w + need; need += alignup(bytes); return p; };
    float* dinv     = (float*)carve(NN * 4);
    int*   cnt      = (int*)  carve(NN * 4);
    int*   rowstart = (int*)  carve((NN + 1) * 4);
    int*   bsum     = (int*)  carve(NB * 4);
    int*   slot     = (int*)  carve((size_t)NE * 4);
    int2*  edat     = (int2*) carve((size_t)NE * 8);
    unsigned short* Hb  = (unsigned short*)carve((size_t)NN * NC * 2);
    unsigned short* Ab  = (unsigned short*)carve((size_t)NN * NC * 2);
    unsigned short* Xb  = (unsigned short*)carve((size_t)NN * NC * 2);
    unsigned short* Wb1 = (unsigned short*)carve(128 * 128 * 2);
    unsigned short* Wb2 = (unsigned short*)carve(128 * 128 * 2);
    unsigned short* Wb3 = (unsigned short*)carve(128 * 128 * 2);
    if (need > ws_size) return;  // workspace too small -> visible validation failure

    const int gN  = (NN + 255) / 256;
    const int gE  = (NE + 255) / 256;
    const int gE4 = (NE4 + 255) / 256;
    const int gGemm = (NN + 127) / 128;
    const int gW    = (2048 + 255) / 256;

    // CSR build; X->bf16 conversion hidden under the count atomic drain
    k_init<<<gN, 256, 0, stream>>>(cnt);
    k_count<<<gE4, 256, 0, stream>>>((const int4*)dstp, cnt, (int4*)slot,
                                     (const float4*)X, (uint4*)Xb);
    k_wconv<<<gW, 256, 0, stream>>>(W1, Wb1);
    k_wconv<<<gW, 256, 0, stream>>>(W2, Wb2);
    k_wconv<<<gW, 256, 0, stream>>>(W3, Wb3);
    k_scan1<<<NB, 256, 0, stream>>>(cnt, bsum);
    k_scan2<<<1, 64, 0, stream>>>(bsum, rowstart);
    k_scan3<<<NB, 256, 0, stream>>>(cnt, bsum, rowstart);
    k_fill<<<gE4, 256, 0, stream>>>((const int4*)srcp, (const int4*)dstp, (const float4*)ew,
                                    rowstart, (const int4*)slot, edat);
    k_degdinv<<<gN, 256, 0, stream>>>(rowstart, edat, dinv);
    k_norm<<<gE, 256, 0, stream>>>(dinv, edat);

    // layer 1
    k_gemm<<<gGemm, 256, 0, stream>>>(Xb, Wb1, Hb);
    k_agg<1, 1><<<GAGG, 256, 0, stream>>>(Hb, rowstart, edat, dinv, b1, Ab);
    // layer 2
    k_gemm<<<gGemm, 256, 0, stream>>>(Ab, Wb2, Hb);
    k_agg<1, 1><<<GAGG, 256, 0, stream>>>(Hb, rowstart, edat, dinv, b2, Ab);
    // layer 3
    k_gemm<<<gGemm, 256, 0, stream>>>(Ab, Wb3, Hb);
    k_agg<0, 0><<<GAGG, 256, 0, stream>>>(Hb, rowstart, edat, dinv, b3, out);
}

// Round 15
// 385.977 us; speedup vs baseline: 1.3775x; 1.0041x over previous
//
#include <hip/hip_runtime.h>
#include <hip/hip_bf16.h>
#include <cstdint>

#define NN 100000
#define NE 1600000
#define NC 128

constexpr int SCAN_SEG = 1024;
constexpr int NB = (NN + SCAN_SEG - 1) / SCAN_SEG; // 98
constexpr int NE4 = NE / 4;                        // 400000
constexpr int NCHUNK = (NN + 31) / 32;             // 3125 32-node chunks
constexpr int GAGG = ((NCHUNK + 3) / 4) * 8;       // 6256 blocks: b%8 -> XCD; half=(b%8)>>2
constexpr int GE4  = (NE4 + 255) / 256;            // 1563 fill blocks
constexpr int GGEMM = (NN + 127) / 128;            // 782 gemm blocks

typedef __attribute__((ext_vector_type(8))) short short8;
typedef __attribute__((ext_vector_type(4))) float f32x4;

// ---------------- bf16 helpers ----------------

__device__ __forceinline__ unsigned int f2bf(float f) {
    unsigned int u = __float_as_uint(f);
    u = (u + 0x7fffu + ((u >> 16) & 1u)) >> 16;   // RNE
    return u & 0xffffu;
}
#define BFLO(u) __uint_as_float((u) << 16)
#define BFHI(u) __uint_as_float((u) & 0xffff0000u)

// ---------------- CSR build ----------------

__global__ __launch_bounds__(256) void k_init(int* __restrict__ cnt) {
    int i = blockIdx.x * 256 + threadIdx.x;
    if (i < NN) cnt[i] = 0;
}

// count atomics + slot write, with X->bf16 conversion folded into the
// atomic-latency shadow.
__global__ __launch_bounds__(256) void k_count(const int4* __restrict__ dst4, int* __restrict__ cnt,
                                               int4* __restrict__ slot4,
                                               const float4* __restrict__ X4, uint4* __restrict__ Xb4) {
    int i = blockIdx.x * 256 + threadIdx.x;
    if (i >= NE4) return;
    int4 d = dst4[i];
    int4 s;
    s.x = atomicAdd(&cnt[d.x], 1);
    s.y = atomicAdd(&cnt[d.y], 1);
    s.z = atomicAdd(&cnt[d.z], 1);
    s.w = atomicAdd(&cnt[d.w], 1);
    #pragma unroll
    for (int c = 0; c < 4; ++c) {
        float4 u = X4[(size_t)i * 8 + c * 2];
        float4 v = X4[(size_t)i * 8 + c * 2 + 1];
        uint4 o;
        o.x = f2bf(u.x) | (f2bf(u.y) << 16);
        o.y = f2bf(u.z) | (f2bf(u.w) << 16);
        o.z = f2bf(v.x) | (f2bf(v.y) << 16);
        o.w = f2bf(v.z) | (f2bf(v.w) << 16);
        Xb4[(size_t)i * 4 + c] = o;
    }
    slot4[i] = s;
}

// ---------------- W -> fragment-swizzled bf16 (all 3 layers, one launch) ----------------

__global__ __launch_bounds__(256) void k_wconv3(const float* __restrict__ W1, const float* __restrict__ W2,
                                                const float* __restrict__ W3,
                                                unsigned short* __restrict__ Wb1, unsigned short* __restrict__ Wb2,
                                                unsigned short* __restrict__ Wb3) {
    int jj = blockIdx.x * 256 + threadIdx.x;
    if (jj >= 6144) return;
    int which = jj >> 11;
    int j = jj & 2047;
    const float* W = (which == 0) ? W1 : (which == 1) ? W2 : W3;
    unsigned short* Wb = (which == 0) ? Wb1 : (which == 1) ? Wb2 : Wb3;
    int f = j >> 6, l = j & 63;
    int ks = f >> 3, ct = f & 7;
    int kb  = ks * 32 + (l >> 4) * 8;
    int col = ct * 16 + (l & 15);
    uint4 o;
    o.x = f2bf(W[(size_t)(kb + 0) * NC + col]) | (f2bf(W[(size_t)(kb + 1) * NC + col]) << 16);
    o.y = f2bf(W[(size_t)(kb + 2) * NC + col]) | (f2bf(W[(size_t)(kb + 3) * NC + col]) << 16);
    o.z = f2bf(W[(size_t)(kb + 4) * NC + col]) | (f2bf(W[(size_t)(kb + 5) * NC + col]) << 16);
    o.w = f2bf(W[(size_t)(kb + 6) * NC + col]) | (f2bf(W[(size_t)(kb + 7) * NC + col]) << 16);
    *(uint4*)(Wb + (size_t)j * 8) = o;
}

// ---------------- exclusive scan of cnt -> rowstart ----------------

__global__ __launch_bounds__(256) void k_scan1(const int* __restrict__ cnt, int* __restrict__ bsum) {
    __shared__ int sdata[256];
    int b = blockIdx.x, t = threadIdx.x;
    int base = b * SCAN_SEG + t * 4;
    int s = 0;
    #pragma unroll
    for (int j = 0; j < 4; ++j) { int idx = base + j; if (idx < NN) s += cnt[idx]; }
    sdata[t] = s; __syncthreads();
    for (int off = 128; off > 0; off >>= 1) {
        if (t < off) sdata[t] += sdata[t + off];
        __syncthreads();
    }
    if (t == 0) bsum[b] = sdata[0];
}

__global__ void k_scan2(int* __restrict__ bsum, int* __restrict__ rowstart) {
    if (threadIdx.x == 0 && blockIdx.x == 0) {
        int run = 0;
        for (int i = 0; i < NB; ++i) { int v = bsum[i]; bsum[i] = run; run += v; }
        rowstart[NN] = run;  // == NE
    }
}

__global__ __launch_bounds__(256) void k_scan3(const int* __restrict__ cnt, const int* __restrict__ bsum,
                                               int* __restrict__ rowstart) {
    __shared__ int sdata[256];
    int b = blockIdx.x, t = threadIdx.x;
    int base = b * SCAN_SEG + t * 4;
    int v[4]; int vsum = 0;
    #pragma unroll
    for (int j = 0; j < 4; ++j) { int idx = base + j; v[j] = (idx < NN) ? cnt[idx] : 0; vsum += v[j]; }
    sdata[t] = vsum; __syncthreads();
    int incl = vsum;
    for (int off = 1; off < 256; off <<= 1) {
        int add = (t >= off) ? sdata[t - off] : 0;
        __syncthreads();
        incl += add;
        sdata[t] = incl;
        __syncthreads();
    }
    int run = bsum[b] + (incl - vsum);
    #pragma unroll
    for (int j = 0; j < 4; ++j) {
        int idx = base + j;
        if (idx < NN) { rowstart[idx] = run; run += v[j]; }
    }
}

// ---------------- fused: CSR fill + layer-1 MFMA GEMM (block-range split) ----------------
// Blocks [0, GE4): scatter edat (fire-and-forget stores, no atomics).
// Blocks [GE4, GE4+GGEMM): Hb = bf16(Xb @ W1) via MFMA (no LDS).
// Independent outputs; gemm blocks overlap the fill write drain.

__global__ __launch_bounds__(256) void k_fillgemm1(const int4* __restrict__ src4, const int4* __restrict__ dst4,
                                                   const float4* __restrict__ w4, const int* __restrict__ rowstart,
                                                   const int4* __restrict__ slot4, int2* __restrict__ edat,
                                                   const unsigned short* __restrict__ Ab,
                                                   const unsigned short* __restrict__ Wb,
                                                   unsigned short* __restrict__ Hb) {
    int t = threadIdx.x;
    if ((int)blockIdx.x < GE4) {
        int i = blockIdx.x * 256 + t;
        if (i < NE4) {
            int4 s = src4[i]; int4 d = dst4[i]; float4 wv = w4[i]; int4 sl = slot4[i];
            edat[rowstart[d.x] + sl.x] = make_int2(s.x, __float_as_int(wv.x));
            edat[rowstart[d.y] + sl.y] = make_int2(s.y, __float_as_int(wv.y));
            edat[rowstart[d.z] + sl.z] = make_int2(s.z, __float_as_int(wv.z));
            edat[rowstart[d.w] + sl.w] = make_int2(s.w, __float_as_int(wv.w));
        }
        return;
    }

    int w = t >> 6, l = t & 63;
    int lr = l & 15, lk = l >> 4;
    int rbase = (blockIdx.x - GE4) * 128 + w * 32;

    f32x4 acc[2][8];
    #pragma unroll
    for (int rt = 0; rt < 2; ++rt)
        #pragma unroll
        for (int ct = 0; ct < 8; ++ct) acc[rt][ct] = (f32x4){0.f, 0.f, 0.f, 0.f};

    int r0 = rbase + lr;      if (r0 > NN - 1) r0 = NN - 1;
    int r1 = rbase + 16 + lr; if (r1 > NN - 1) r1 = NN - 1;
    const unsigned short* a0p = Ab + (size_t)r0 * NC + lk * 8;
    const unsigned short* a1p = Ab + (size_t)r1 * NC + lk * 8;
    const unsigned short* wp  = Wb + (size_t)l * 8;

    #pragma unroll
    for (int ks = 0; ks < 4; ++ks) {
        short8 a0 = *(const short8*)(a0p + ks * 32);
        short8 a1 = *(const short8*)(a1p + ks * 32);
        #pragma unroll
        for (int ct = 0; ct < 8; ++ct) {
            short8 b = *(const short8*)(wp + (size_t)(ks * 8 + ct) * 512);
            acc[0][ct] = __builtin_amdgcn_mfma_f32_16x16x32_bf16(a0, b, acc[0][ct], 0, 0, 0);
            acc[1][ct] = __builtin_amdgcn_mfma_f32_16x16x32_bf16(a1, b, acc[1][ct], 0, 0, 0);
        }
    }

    #pragma unroll
    for (int rt = 0; rt < 2; ++rt) {
        int rowb = rbase + rt * 16 + lk * 4;
        #pragma unroll
        for (int r = 0; r < 4; ++r) {
            int row = rowb + r;
            if (row < NN) {
                unsigned short* hp = Hb + (size_t)row * NC + lr;
                #pragma unroll
                for (int ct = 0; ct < 8; ++ct)
                    hp[ct * 16] = (unsigned short)f2bf(acc[rt][ct][r]);
            }
        }
    }
}

// ---------------- deg -> dinv (no atomics): deg = 1 + sum_row(w) ----------------

__global__ __launch_bounds__(256) void k_degdinv(const int* __restrict__ rs, const int2* __restrict__ edat,
                                                 float* __restrict__ dinv) {
    int i = blockIdx.x * 256 + threadIdx.x;
    if (i < NN) {
        float dg = 1.0f;  // self-loop weight
        int p1 = rs[i + 1];
        for (int p = rs[i]; p < p1; ++p) dg += __int_as_float(edat[p].y);
        dinv[i] = (dg > 0.0f) ? (1.0f / sqrtf(fmaxf(dg, 1e-12f))) : 0.0f;
    }
}

// ---------------- MFMA GEMM: Hb = bf16( Ab @ W ) (layers 2,3) ----------------

__global__ __launch_bounds__(256) void k_gemm(const unsigned short* __restrict__ Ab,
                                              const unsigned short* __restrict__ Wb,
                                              unsigned short* __restrict__ Hb) {
    int t = threadIdx.x;
    int w = t >> 6, l = t & 63;
    int lr = l & 15, lk = l >> 4;
    int rbase = blockIdx.x * 128 + w * 32;

    f32x4 acc[2][8];
    #pragma unroll
    for (int rt = 0; rt < 2; ++rt)
        #pragma unroll
        for (int ct = 0; ct < 8; ++ct) acc[rt][ct] = (f32x4){0.f, 0.f, 0.f, 0.f};

    int r0 = rbase + lr;      if (r0 > NN - 1) r0 = NN - 1;
    int r1 = rbase + 16 + lr; if (r1 > NN - 1) r1 = NN - 1;
    const unsigned short* a0p = Ab + (size_t)r0 * NC + lk * 8;
    const unsigned short* a1p = Ab + (size_t)r1 * NC + lk * 8;
    const unsigned short* wp  = Wb + (size_t)l * 8;

    #pragma unroll
    for (int ks = 0; ks < 4; ++ks) {
        short8 a0 = *(const short8*)(a0p + ks * 32);
        short8 a1 = *(const short8*)(a1p + ks * 32);
        #pragma unroll
        for (int ct = 0; ct < 8; ++ct) {
            short8 b = *(const short8*)(wp + (size_t)(ks * 8 + ct) * 512);
            acc[0][ct] = __builtin_amdgcn_mfma_f32_16x16x32_bf16(a0, b, acc[0][ct], 0, 0, 0);
            acc[1][ct] = __builtin_amdgcn_mfma_f32_16x16x32_bf16(a1, b, acc[1][ct], 0, 0, 0);
        }
    }

    #pragma unroll
    for (int rt = 0; rt < 2; ++rt) {
        int rowb = rbase + rt * 16 + lk * 4;
        #pragma unroll
        for (int r = 0; r < 4; ++r) {
            int row = rowb + r;
            if (row < NN) {
                unsigned short* hp = Hb + (size_t)row * NC + lr;
                #pragma unroll
                for (int ct = 0; ct < 8; ++ct)
                    hp[ct * 16] = (unsigned short)f2bf(acc[rt][ct][r]);
            }
        }
    }
}

// ---------------- aggregation: channel-half XCD split ----------------
// Block b: half h=(b%8)>>2, 32-node chunk=(b>>3)*4+(b&3). 8-lane group owns one
// node's 64-channel half; per edge ONE 128 B line. 8-deep unroll.
// NORMW=1 (layer 1): edat.y = RAW w; nw = dinv[src]*w computed in-flight and
// written to the SEPARATE nrm[] array (h==0 && cl==0 only; nrm unread in layer 1
// -> race-free). NORMW=0 (layers 2,3): weight read from nrm[p].
// OB=1: write bf16 Ab; OB=0: f32 out.

#define AGG_FMA8(NW, U)                                                                    \
    do {                                                                                   \
        acc0.x = fmaf((NW), BFLO((U).x), acc0.x); acc0.y = fmaf((NW), BFHI((U).x), acc0.y);\
        acc0.z = fmaf((NW), BFLO((U).y), acc0.z); acc0.w = fmaf((NW), BFHI((U).y), acc0.w);\
        acc1.x = fmaf((NW), BFLO((U).z), acc1.x); acc1.y = fmaf((NW), BFHI((U).z), acc1.y);\
        acc1.z = fmaf((NW), BFLO((U).w), acc1.z); acc1.w = fmaf((NW), BFHI((U).w), acc1.w);\
    } while (0)

template <int RELU, int OB, int NORMW>
__global__ __launch_bounds__(256) void k_agg(const unsigned short* __restrict__ Hb, const int* __restrict__ rs,
                                             const int2* __restrict__ edat, float* __restrict__ nrm,
                                             const float* __restrict__ dinv, const float* __restrict__ bias,
                                             void* __restrict__ outv) {
    int b = blockIdx.x;
    int h     = (b & 7) >> 2;             // channel half 0/1
    int chunk = (b >> 3) * 4 + (b & 3);   // 32-node chunk
    if (chunk >= NCHUNK) return;
    int grp  = threadIdx.x >> 3;          // 0..31: node within chunk
    int cl   = threadIdx.x & 7;           // owns channels h*64 + cl*8 .. +7
    int node = chunk * 32 + grp;
    if (node >= NN) return;
    int cb = h * 64 + cl * 8;
    bool wr = (h == 0) && (cl == 0);

    float di = dinv[node];
    float4 acc0, acc1;

    {
        uint4 U = *(const uint4*)(Hb + (size_t)node * NC + cb);
        acc0.x = BFLO(U.x) * di; acc0.y = BFHI(U.x) * di;
        acc0.z = BFLO(U.y) * di; acc0.w = BFHI(U.y) * di;
        acc1.x = BFLO(U.z) * di; acc1.y = BFHI(U.z) * di;
        acc1.z = BFLO(U.w) * di; acc1.w = BFHI(U.w) * di;
    }

    int p0 = rs[node], p1 = rs[node + 1];
    int p = p0;
    for (; p + 7 < p1; p += 8) {
        int2 e0 = edat[p+0], e1 = edat[p+1], e2 = edat[p+2], e3 = edat[p+3];
        int2 e4 = edat[p+4], e5 = edat[p+5], e6 = edat[p+6], e7 = edat[p+7];
        float n0, n1, n2, n3, n4, n5, n6, n7;
        if (NORMW) {
            n0 = dinv[e0.x] * __int_as_float(e0.y);
            n1 = dinv[e1.x] * __int_as_float(e1.y);
            n2 = dinv[e2.x] * __int_as_float(e2.y);
            n3 = dinv[e3.x] * __int_as_float(e3.y);
            n4 = dinv[e4.x] * __int_as_float(e4.y);
            n5 = dinv[e5.x] * __int_as_float(e5.y);
            n6 = dinv[e6.x] * __int_as_float(e6.y);
            n7 = dinv[e7.x] * __int_as_float(e7.y);
            if (wr) {
                nrm[p+0] = n0; nrm[p+1] = n1; nrm[p+2] = n2; nrm[p+3] = n3;
                nrm[p+4] = n4; nrm[p+5] = n5; nrm[p+6] = n6; nrm[p+7] = n7;
            }
        } else {
            n0 = nrm[p+0]; n1 = nrm[p+1]; n2 = nrm[p+2]; n3 = nrm[p+3];
            n4 = nrm[p+4]; n5 = nrm[p+5]; n6 = nrm[p+6]; n7 = nrm[p+7];
        }
        uint4 U0 = *(const uint4*)(Hb + (size_t)e0.x * NC + cb);
        uint4 U1 = *(const uint4*)(Hb + (size_t)e1.x * NC + cb);
        uint4 U2 = *(const uint4*)(Hb + (size_t)e2.x * NC + cb);
        uint4 U3 = *(const uint4*)(Hb + (size_t)e3.x * NC + cb);
        uint4 U4 = *(const uint4*)(Hb + (size_t)e4.x * NC + cb);
        uint4 U5 = *(const uint4*)(Hb + (size_t)e5.x * NC + cb);
        uint4 U6 = *(const uint4*)(Hb + (size_t)e6.x * NC + cb);
        uint4 U7 = *(const uint4*)(Hb + (size_t)e7.x * NC + cb);
        AGG_FMA8(n0, U0); AGG_FMA8(n1, U1); AGG_FMA8(n2, U2); AGG_FMA8(n3, U3);
        AGG_FMA8(n4, U4); AGG_FMA8(n5, U5); AGG_FMA8(n6, U6); AGG_FMA8(n7, U7);
    }
    for (; p + 3 < p1; p += 4) {
        int2 e0 = edat[p+0], e1 = edat[p+1], e2 = edat[p+2], e3 = edat[p+3];
        float n0, n1, n2, n3;
        if (NORMW) {
            n0 = dinv[e0.x] * __int_as_float(e0.y);
            n1 = dinv[e1.x] * __int_as_float(e1.y);
            n2 = dinv[e2.x] * __int_as_float(e2.y);
            n3 = dinv[e3.x] * __int_as_float(e3.y);
            if (wr) { nrm[p+0] = n0; nrm[p+1] = n1; nrm[p+2] = n2; nrm[p+3] = n3; }
        } else {
            n0 = nrm[p+0]; n1 = nrm[p+1]; n2 = nrm[p+2]; n3 = nrm[p+3];
        }
        uint4 U0 = *(const uint4*)(Hb + (size_t)e0.x * NC + cb);
        uint4 U1 = *(const uint4*)(Hb + (size_t)e1.x * NC + cb);
        uint4 U2 = *(const uint4*)(Hb + (size_t)e2.x * NC + cb);
        uint4 U3 = *(const uint4*)(Hb + (size_t)e3.x * NC + cb);
        AGG_FMA8(n0, U0); AGG_FMA8(n1, U1); AGG_FMA8(n2, U2); AGG_FMA8(n3, U3);
    }
    for (; p < p1; ++p) {
        int2 e0 = edat[p];
        float n0;
        if (NORMW) {
            n0 = dinv[e0.x] * __int_as_float(e0.y);
            if (wr) nrm[p] = n0;
        } else {
            n0 = nrm[p];
        }
        uint4 U0 = *(const uint4*)(Hb + (size_t)e0.x * NC + cb);
        AGG_FMA8(n0, U0);
    }

    const float4* bp = (const float4*)(bias + cb);
    float4 bv0 = bp[0], bv1 = bp[1];
    acc0.x = fmaf(acc0.x, di, bv0.x); acc0.y = fmaf(acc0.y, di, bv0.y);
    acc0.z = fmaf(acc0.z, di, bv0.z); acc0.w = fmaf(acc0.w, di, bv0.w);
    acc1.x = fmaf(acc1.x, di, bv1.x); acc1.y = fmaf(acc1.y, di, bv1.y);
    acc1.z = fmaf(acc1.z, di, bv1.z); acc1.w = fmaf(acc1.w, di, bv1.w);
    if (RELU) {
        acc0.x = fmaxf(acc0.x, 0.f); acc0.y = fmaxf(acc0.y, 0.f);
        acc0.z = fmaxf(acc0.z, 0.f); acc0.w = fmaxf(acc0.w, 0.f);
        acc1.x = fmaxf(acc1.x, 0.f); acc1.y = fmaxf(acc1.y, 0.f);
        acc1.z = fmaxf(acc1.z, 0.f); acc1.w = fmaxf(acc1.w, 0.f);
    }
    if (OB) {
        unsigned short* op = (unsigned short*)outv + (size_t)node * NC + cb;
        uint4 o;
        o.x = f2bf(acc0.x) | (f2bf(acc0.y) << 16);
        o.y = f2bf(acc0.z) | (f2bf(acc0.w) << 16);
        o.z = f2bf(acc1.x) | (f2bf(acc1.y) << 16);
        o.w = f2bf(acc1.z) | (f2bf(acc1.w) << 16);
        *(uint4*)op = o;
    } else {
        float* op = (float*)outv + (size_t)node * NC + cb;
        *(float4*)op       = acc0;
        *(float4*)(op + 4) = acc1;
    }
}

// ---------------- launch ----------------

static inline size_t alignup(size_t x) { return (x + 255) & ~(size_t)255; }

extern "C" void kernel_launch(void* const* d_in, const int* in_sizes, int n_in,
                              void* d_out, int out_size, void* d_ws, size_t ws_size,
                              hipStream_t stream) {
    const float* X  = (const float*)d_in[0];
    const int*   ei = (const int*)d_in[1];          // [2, NE]: row0 = src, row1 = dst
    const float* ew = (const float*)d_in[2];
    const float* W1 = (const float*)d_in[3]; const float* b1 = (const float*)d_in[4];
    const float* W2 = (const float*)d_in[5]; const float* b2 = (const float*)d_in[6];
    const float* W3 = (const float*)d_in[7]; const float* b3 = (const float*)d_in[8];
    float* out = (float*)d_out;

    const int* srcp = ei;
    const int* dstp = ei + NE;

    // workspace carve
    char* w = (char*)d_ws;
    size_t need = 0;
    auto carve = [&](size_t bytes) { char* p = w + need; need += alignup(bytes); return p; };
    float* dinv     = (float*)carve(NN * 4);
    int*   cnt      = (int*)  carve(NN * 4);
    int*   rowstart = (int*)  carve((NN + 1) * 4);
    int*   bsum     = (int*)  carve(NB * 4);
    int*   slot     = (int*)  carve((size_t)NE * 4);
    int2*  edat     = (int2*) carve((size_t)NE * 8);
    float* nrm      = (float*)carve((size_t)NE * 4);
    unsigned short* Hb  = (unsigned short*)carve((size_t)NN * NC * 2);
    unsigned short* Ab  = (unsigned short*)carve((size_t)NN * NC * 2);
    unsigned short* Xb  = (unsigned short*)carve((size_t)NN * NC * 2);
    unsigned short* Wb1 = (unsigned short*)carve(128 * 128 * 2);
    unsigned short* Wb2 = (unsigned short*)carve(128 * 128 * 2);
    unsigned short* Wb3 = (unsigned short*)carve(128 * 128 * 2);
    if (need > ws_size) return;  // workspace too small -> visible validation failure

    const int gN  = (NN + 255) / 256;

    // CSR build; X->bf16 conversion hidden under the count atomic drain
    k_init<<<gN, 256, 0, stream>>>(cnt);
    k_count<<<GE4, 256, 0, stream>>>((const int4*)dstp, cnt, (int4*)slot,
                                     (const float4*)X, (uint4*)Xb);
    k_wconv3<<<(6144 + 255) / 256, 256, 0, stream>>>(W1, W2, W3, Wb1, Wb2, Wb3);
    k_scan1<<<NB, 256, 0, stream>>>(cnt, bsum);
    k_scan2<<<1, 64, 0, stream>>>(bsum, rowstart);
    k_scan3<<<NB, 256, 0, stream>>>(cnt, bsum, rowstart);
    // fill overlapped with layer-1 GEMM (both independent, no LDS)
    k_fillgemm1<<<GE4 + GGEMM, 256, 0, stream>>>((const int4*)srcp, (const int4*)dstp, (const float4*)ew,
                                                 rowstart, (const int4*)slot, edat, Xb, Wb1, Hb);
    k_degdinv<<<gN, 256, 0, stream>>>(rowstart, edat, dinv);

    // layer 1 (norm fold: nw = dinv[src]*w computed in-flight, written to nrm[] for layers 2-3)
    k_agg<1, 1, 1><<<GAGG, 256, 0, stream>>>(Hb, rowstart, edat, nrm, dinv, b1, Ab);
    // layer 2
    k_gemm<<<GGEMM, 256, 0, stream>>>(Ab, Wb2, Hb);
    k_agg<1, 1, 0><<<GAGG, 256, 0, stream>>>(Hb, rowstart, edat, nrm, dinv, b2, Ab);
    // layer 3
    k_gemm<<<GGEMM, 256, 0, stream>>>(Ab, Wb3, Hb);
    k_agg<0, 0, 0><<<GAGG, 256, 0, stream>>>(Hb, rowstart, edat, nrm, dinv, b3, out);
}

// Round 16
// 377.330 us; speedup vs baseline: 1.4090x; 1.0229x over previous
//
#include <hip/hip_runtime.h>
#include <hip/hip_bf16.h>
#include <cstdint>

#define NN 100000
#define NE 1600000
#define NC 128

constexpr int SCAN_SEG = 1024;
constexpr int NB = (NN + SCAN_SEG - 1) / SCAN_SEG; // 98
constexpr int NE4 = NE / 4;                        // 400000
constexpr int NCHUNK = (NN + 31) / 32;             // 3125 32-node chunks
constexpr int GAGG = ((NCHUNK + 3) / 4) * 8;       // 6256 blocks: b%8 -> XCD; half=(b%8)>>2
constexpr int GE4  = (NE4 + 255) / 256;            // 1563 fill blocks
constexpr int GGEMM = (NN + 127) / 128;            // 782 gemm blocks

typedef __attribute__((ext_vector_type(8))) short short8;
typedef __attribute__((ext_vector_type(4))) float f32x4;

// ---------------- bf16 helpers ----------------

__device__ __forceinline__ unsigned int f2bf(float f) {
    unsigned int u = __float_as_uint(f);
    u = (u + 0x7fffu + ((u >> 16) & 1u)) >> 16;   // RNE
    return u & 0xffffu;
}
#define BFLO(u) __uint_as_float((u) << 16)
#define BFHI(u) __uint_as_float((u) & 0xffff0000u)

// ---------------- CSR build ----------------

__global__ __launch_bounds__(256) void k_init(int* __restrict__ cnt) {
    int i = blockIdx.x * 256 + threadIdx.x;
    if (i < NN) cnt[i] = 0;
}

// count atomics + slot write, with X->bf16 conversion folded into the
// atomic-latency shadow.
__global__ __launch_bounds__(256) void k_count(const int4* __restrict__ dst4, int* __restrict__ cnt,
                                               int4* __restrict__ slot4,
                                               const float4* __restrict__ X4, uint4* __restrict__ Xb4) {
    int i = blockIdx.x * 256 + threadIdx.x;
    if (i >= NE4) return;
    int4 d = dst4[i];
    int4 s;
    s.x = atomicAdd(&cnt[d.x], 1);
    s.y = atomicAdd(&cnt[d.y], 1);
    s.z = atomicAdd(&cnt[d.z], 1);
    s.w = atomicAdd(&cnt[d.w], 1);
    #pragma unroll
    for (int c = 0; c < 4; ++c) {
        float4 u = X4[(size_t)i * 8 + c * 2];
        float4 v = X4[(size_t)i * 8 + c * 2 + 1];
        uint4 o;
        o.x = f2bf(u.x) | (f2bf(u.y) << 16);
        o.y = f2bf(u.z) | (f2bf(u.w) << 16);
        o.z = f2bf(v.x) | (f2bf(v.y) << 16);
        o.w = f2bf(v.z) | (f2bf(v.w) << 16);
        Xb4[(size_t)i * 4 + c] = o;
    }
    slot4[i] = s;
}

// ---------------- W -> fragment-swizzled bf16 (all 3 layers, one launch) ----------------

__global__ __launch_bounds__(256) void k_wconv3(const float* __restrict__ W1, const float* __restrict__ W2,
                                                const float* __restrict__ W3,
                                                unsigned short* __restrict__ Wb1, unsigned short* __restrict__ Wb2,
                                                unsigned short* __restrict__ Wb3) {
    int jj = blockIdx.x * 256 + threadIdx.x;
    if (jj >= 6144) return;
    int which = jj >> 11;
    int j = jj & 2047;
    const float* W = (which == 0) ? W1 : (which == 1) ? W2 : W3;
    unsigned short* Wb = (which == 0) ? Wb1 : (which == 1) ? Wb2 : Wb3;
    int f = j >> 6, l = j & 63;
    int ks = f >> 3, ct = f & 7;
    int kb  = ks * 32 + (l >> 4) * 8;
    int col = ct * 16 + (l & 15);
    uint4 o;
    o.x = f2bf(W[(size_t)(kb + 0) * NC + col]) | (f2bf(W[(size_t)(kb + 1) * NC + col]) << 16);
    o.y = f2bf(W[(size_t)(kb + 2) * NC + col]) | (f2bf(W[(size_t)(kb + 3) * NC + col]) << 16);
    o.z = f2bf(W[(size_t)(kb + 4) * NC + col]) | (f2bf(W[(size_t)(kb + 5) * NC + col]) << 16);
    o.w = f2bf(W[(size_t)(kb + 6) * NC + col]) | (f2bf(W[(size_t)(kb + 7) * NC + col]) << 16);
    *(uint4*)(Wb + (size_t)j * 8) = o;
}

// ---------------- exclusive scan of cnt -> rowstart ----------------

__global__ __launch_bounds__(256) void k_scan1(const int* __restrict__ cnt, int* __restrict__ bsum) {
    __shared__ int sdata[256];
    int b = blockIdx.x, t = threadIdx.x;
    int base = b * SCAN_SEG + t * 4;
    int s = 0;
    #pragma unroll
    for (int j = 0; j < 4; ++j) { int idx = base + j; if (idx < NN) s += cnt[idx]; }
    sdata[t] = s; __syncthreads();
    for (int off = 128; off > 0; off >>= 1) {
        if (t < off) sdata[t] += sdata[t + off];
        __syncthreads();
    }
    if (t == 0) bsum[b] = sdata[0];
}

__global__ void k_scan2(int* __restrict__ bsum, int* __restrict__ rowstart) {
    if (threadIdx.x == 0 && blockIdx.x == 0) {
        int run = 0;
        for (int i = 0; i < NB; ++i) { int v = bsum[i]; bsum[i] = run; run += v; }
        rowstart[NN] = run;  // == NE
    }
}

__global__ __launch_bounds__(256) void k_scan3(const int* __restrict__ cnt, const int* __restrict__ bsum,
                                               int* __restrict__ rowstart) {
    __shared__ int sdata[256];
    int b = blockIdx.x, t = threadIdx.x;
    int base = b * SCAN_SEG + t * 4;
    int v[4]; int vsum = 0;
    #pragma unroll
    for (int j = 0; j < 4; ++j) { int idx = base + j; v[j] = (idx < NN) ? cnt[idx] : 0; vsum += v[j]; }
    sdata[t] = vsum; __syncthreads();
    int incl = vsum;
    for (int off = 1; off < 256; off <<= 1) {
        int add = (t >= off) ? sdata[t - off] : 0;
        __syncthreads();
        incl += add;
        sdata[t] = incl;
        __syncthreads();
    }
    int run = bsum[b] + (incl - vsum);
    #pragma unroll
    for (int j = 0; j < 4; ++j) {
        int idx = base + j;
        if (idx < NN) { rowstart[idx] = run; run += v[j]; }
    }
}

// ---------------- fused: CSR fill + layer-1 MFMA GEMM (block-range split) ----------------

__global__ __launch_bounds__(256) void k_fillgemm1(const int4* __restrict__ src4, const int4* __restrict__ dst4,
                                                   const float4* __restrict__ w4, const int* __restrict__ rowstart,
                                                   const int4* __restrict__ slot4, int2* __restrict__ edat,
                                                   const unsigned short* __restrict__ Ab,
                                                   const unsigned short* __restrict__ Wb,
                                                   unsigned short* __restrict__ Hb) {
    int t = threadIdx.x;
    if ((int)blockIdx.x < GE4) {
        int i = blockIdx.x * 256 + t;
        if (i < NE4) {
            int4 s = src4[i]; int4 d = dst4[i]; float4 wv = w4[i]; int4 sl = slot4[i];
            edat[rowstart[d.x] + sl.x] = make_int2(s.x, __float_as_int(wv.x));
            edat[rowstart[d.y] + sl.y] = make_int2(s.y, __float_as_int(wv.y));
            edat[rowstart[d.z] + sl.z] = make_int2(s.z, __float_as_int(wv.z));
            edat[rowstart[d.w] + sl.w] = make_int2(s.w, __float_as_int(wv.w));
        }
        return;
    }

    int w = t >> 6, l = t & 63;
    int lr = l & 15, lk = l >> 4;
    int rbase = (blockIdx.x - GE4) * 128 + w * 32;

    f32x4 acc[2][8];
    #pragma unroll
    for (int rt = 0; rt < 2; ++rt)
        #pragma unroll
        for (int ct = 0; ct < 8; ++ct) acc[rt][ct] = (f32x4){0.f, 0.f, 0.f, 0.f};

    int r0 = rbase + lr;      if (r0 > NN - 1) r0 = NN - 1;
    int r1 = rbase + 16 + lr; if (r1 > NN - 1) r1 = NN - 1;
    const unsigned short* a0p = Ab + (size_t)r0 * NC + lk * 8;
    const unsigned short* a1p = Ab + (size_t)r1 * NC + lk * 8;
    const unsigned short* wp  = Wb + (size_t)l * 8;

    #pragma unroll
    for (int ks = 0; ks < 4; ++ks) {
        short8 a0 = *(const short8*)(a0p + ks * 32);
        short8 a1 = *(const short8*)(a1p + ks * 32);
        #pragma unroll
        for (int ct = 0; ct < 8; ++ct) {
            short8 b = *(const short8*)(wp + (size_t)(ks * 8 + ct) * 512);
            acc[0][ct] = __builtin_amdgcn_mfma_f32_16x16x32_bf16(a0, b, acc[0][ct], 0, 0, 0);
            acc[1][ct] = __builtin_amdgcn_mfma_f32_16x16x32_bf16(a1, b, acc[1][ct], 0, 0, 0);
        }
    }

    #pragma unroll
    for (int rt = 0; rt < 2; ++rt) {
        int rowb = rbase + rt * 16 + lk * 4;
        #pragma unroll
        for (int r = 0; r < 4; ++r) {
            int row = rowb + r;
            if (row < NN) {
                unsigned short* hp = Hb + (size_t)row * NC + lr;
                #pragma unroll
                for (int ct = 0; ct < 8; ++ct)
                    hp[ct * 16] = (unsigned short)f2bf(acc[rt][ct][r]);
            }
        }
    }
}

// ---------------- deg -> dinv (no atomics): deg = 1 + sum_row(w) ----------------

__global__ __launch_bounds__(256) void k_degdinv(const int* __restrict__ rs, const int2* __restrict__ edat,
                                                 float* __restrict__ dinv) {
    int i = blockIdx.x * 256 + threadIdx.x;
    if (i < NN) {
        float dg = 1.0f;  // self-loop weight
        int p1 = rs[i + 1];
        for (int p = rs[i]; p < p1; ++p) dg += __int_as_float(edat[p].y);
        dinv[i] = (dg > 0.0f) ? (1.0f / sqrtf(fmaxf(dg, 1e-12f))) : 0.0f;
    }
}

// ---------------- norm: edat[p].y = bits(dinv[src] * w) ----------------

__global__ __launch_bounds__(256) void k_norm(const float* __restrict__ dinv, int2* __restrict__ edat) {
    int p = blockIdx.x * 256 + threadIdx.x;
    if (p < NE) {
        int2 ed = edat[p];
        edat[p].y = __float_as_int(dinv[ed.x] * __int_as_float(ed.y));
    }
}

// ---------------- MFMA GEMM: Hb = bf16( Ab @ W ) (layers 2,3) ----------------

__global__ __launch_bounds__(256) void k_gemm(const unsigned short* __restrict__ Ab,
                                              const unsigned short* __restrict__ Wb,
                                              unsigned short* __restrict__ Hb) {
    int t = threadIdx.x;
    int w = t >> 6, l = t & 63;
    int lr = l & 15, lk = l >> 4;
    int rbase = blockIdx.x * 128 + w * 32;

    f32x4 acc[2][8];
    #pragma unroll
    for (int rt = 0; rt < 2; ++rt)
        #pragma unroll
        for (int ct = 0; ct < 8; ++ct) acc[rt][ct] = (f32x4){0.f, 0.f, 0.f, 0.f};

    int r0 = rbase + lr;      if (r0 > NN - 1) r0 = NN - 1;
    int r1 = rbase + 16 + lr; if (r1 > NN - 1) r1 = NN - 1;
    const unsigned short* a0p = Ab + (size_t)r0 * NC + lk * 8;
    const unsigned short* a1p = Ab + (size_t)r1 * NC + lk * 8;
    const unsigned short* wp  = Wb + (size_t)l * 8;

    #pragma unroll
    for (int ks = 0; ks < 4; ++ks) {
        short8 a0 = *(const short8*)(a0p + ks * 32);
        short8 a1 = *(const short8*)(a1p + ks * 32);
        #pragma unroll
        for (int ct = 0; ct < 8; ++ct) {
            short8 b = *(const short8*)(wp + (size_t)(ks * 8 + ct) * 512);
            acc[0][ct] = __builtin_amdgcn_mfma_f32_16x16x32_bf16(a0, b, acc[0][ct], 0, 0, 0);
            acc[1][ct] = __builtin_amdgcn_mfma_f32_16x16x32_bf16(a1, b, acc[1][ct], 0, 0, 0);
        }
    }

    #pragma unroll
    for (int rt = 0; rt < 2; ++rt) {
        int rowb = rbase + rt * 16 + lk * 4;
        #pragma unroll
        for (int r = 0; r < 4; ++r) {
            int row = rowb + r;
            if (row < NN) {
                unsigned short* hp = Hb + (size_t)row * NC + lr;
                #pragma unroll
                for (int ct = 0; ct < 8; ++ct)
                    hp[ct * 16] = (unsigned short)f2bf(acc[rt][ct][r]);
            }
        }
    }
}

// ---------------- aggregation: channel-half XCD split (r14 version) ----------------

#define AGG_FMA8(NW, U)                                                                    \
    do {                                                                                   \
        acc0.x = fmaf((NW), BFLO((U).x), acc0.x); acc0.y = fmaf((NW), BFHI((U).x), acc0.y);\
        acc0.z = fmaf((NW), BFLO((U).y), acc0.z); acc0.w = fmaf((NW), BFHI((U).y), acc0.w);\
        acc1.x = fmaf((NW), BFLO((U).z), acc1.x); acc1.y = fmaf((NW), BFHI((U).z), acc1.y);\
        acc1.z = fmaf((NW), BFLO((U).w), acc1.z); acc1.w = fmaf((NW), BFHI((U).w), acc1.w);\
    } while (0)

template <int RELU, int OB>
__global__ __launch_bounds__(256) void k_agg(const unsigned short* __restrict__ Hb, const int* __restrict__ rs,
                                             const int2* __restrict__ edat,
                                             const float* __restrict__ dinv, const float* __restrict__ bias,
                                             void* __restrict__ outv) {
    int b = blockIdx.x;
    int h     = (b & 7) >> 2;             // channel half 0/1
    int chunk = (b >> 3) * 4 + (b & 3);   // 32-node chunk
    if (chunk >= NCHUNK) return;
    int grp  = threadIdx.x >> 3;          // 0..31: node within chunk
    int cl   = threadIdx.x & 7;           // owns channels h*64 + cl*8 .. +7
    int node = chunk * 32 + grp;
    if (node >= NN) return;
    int cb = h * 64 + cl * 8;

    float di = dinv[node];
    float4 acc0, acc1;

    {
        uint4 U = *(const uint4*)(Hb + (size_t)node * NC + cb);
        acc0.x = BFLO(U.x) * di; acc0.y = BFHI(U.x) * di;
        acc0.z = BFLO(U.y) * di; acc0.w = BFHI(U.y) * di;
        acc1.x = BFLO(U.z) * di; acc1.y = BFHI(U.z) * di;
        acc1.z = BFLO(U.w) * di; acc1.w = BFHI(U.w) * di;
    }

    int p0 = rs[node], p1 = rs[node + 1];
    int p = p0;
    for (; p + 7 < p1; p += 8) {
        int2 e0 = edat[p+0], e1 = edat[p+1], e2 = edat[p+2], e3 = edat[p+3];
        int2 e4 = edat[p+4], e5 = edat[p+5], e6 = edat[p+6], e7 = edat[p+7];
        uint4 U0 = *(const uint4*)(Hb + (size_t)e0.x * NC + cb);
        uint4 U1 = *(const uint4*)(Hb + (size_t)e1.x * NC + cb);
        uint4 U2 = *(const uint4*)(Hb + (size_t)e2.x * NC + cb);
        uint4 U3 = *(const uint4*)(Hb + (size_t)e3.x * NC + cb);
        uint4 U4 = *(const uint4*)(Hb + (size_t)e4.x * NC + cb);
        uint4 U5 = *(const uint4*)(Hb + (size_t)e5.x * NC + cb);
        uint4 U6 = *(const uint4*)(Hb + (size_t)e6.x * NC + cb);
        uint4 U7 = *(const uint4*)(Hb + (size_t)e7.x * NC + cb);
        AGG_FMA8(__int_as_float(e0.y), U0); AGG_FMA8(__int_as_float(e1.y), U1);
        AGG_FMA8(__int_as_float(e2.y), U2); AGG_FMA8(__int_as_float(e3.y), U3);
        AGG_FMA8(__int_as_float(e4.y), U4); AGG_FMA8(__int_as_float(e5.y), U5);
        AGG_FMA8(__int_as_float(e6.y), U6); AGG_FMA8(__int_as_float(e7.y), U7);
    }
    for (; p + 3 < p1; p += 4) {
        int2 e0 = edat[p+0], e1 = edat[p+1], e2 = edat[p+2], e3 = edat[p+3];
        uint4 U0 = *(const uint4*)(Hb + (size_t)e0.x * NC + cb);
        uint4 U1 = *(const uint4*)(Hb + (size_t)e1.x * NC + cb);
        uint4 U2 = *(const uint4*)(Hb + (size_t)e2.x * NC + cb);
        uint4 U3 = *(const uint4*)(Hb + (size_t)e3.x * NC + cb);
        AGG_FMA8(__int_as_float(e0.y), U0); AGG_FMA8(__int_as_float(e1.y), U1);
        AGG_FMA8(__int_as_float(e2.y), U2); AGG_FMA8(__int_as_float(e3.y), U3);
    }
    for (; p < p1; ++p) {
        int2 e0 = edat[p];
        uint4 U0 = *(const uint4*)(Hb + (size_t)e0.x * NC + cb);
        AGG_FMA8(__int_as_float(e0.y), U0);
    }

    const float4* bp = (const float4*)(bias + cb);
    float4 bv0 = bp[0], bv1 = bp[1];
    acc0.x = fmaf(acc0.x, di, bv0.x); acc0.y = fmaf(acc0.y, di, bv0.y);
    acc0.z = fmaf(acc0.z, di, bv0.z); acc0.w = fmaf(acc0.w, di, bv0.w);
    acc1.x = fmaf(acc1.x, di, bv1.x); acc1.y = fmaf(acc1.y, di, bv1.y);
    acc1.z = fmaf(acc1.z, di, bv1.z); acc1.w = fmaf(acc1.w, di, bv1.w);
    if (RELU) {
        acc0.x = fmaxf(acc0.x, 0.f); acc0.y = fmaxf(acc0.y, 0.f);
        acc0.z = fmaxf(acc0.z, 0.f); acc0.w = fmaxf(acc0.w, 0.f);
        acc1.x = fmaxf(acc1.x, 0.f); acc1.y = fmaxf(acc1.y, 0.f);
        acc1.z = fmaxf(acc1.z, 0.f); acc1.w = fmaxf(acc1.w, 0.f);
    }
    if (OB) {
        unsigned short* op = (unsigned short*)outv + (size_t)node * NC + cb;
        uint4 o;
        o.x = f2bf(acc0.x) | (f2bf(acc0.y) << 16);
        o.y = f2bf(acc0.z) | (f2bf(acc0.w) << 16);
        o.z = f2bf(acc1.x) | (f2bf(acc1.y) << 16);
        o.w = f2bf(acc1.z) | (f2bf(acc1.w) << 16);
        *(uint4*)op = o;
    } else {
        float* op = (float*)outv + (size_t)node * NC + cb;
        *(float4*)op       = acc0;
        *(float4*)(op + 4) = acc1;
    }
}

// ---------------- launch ----------------

static inline size_t alignup(size_t x) { return (x + 255) & ~(size_t)255; }

extern "C" void kernel_launch(void* const* d_in, const int* in_sizes, int n_in,
                              void* d_out, int out_size, void* d_ws, size_t ws_size,
                              hipStream_t stream) {
    const float* X  = (const float*)d_in[0];
    const int*   ei = (const int*)d_in[1];          // [2, NE]: row0 = src, row1 = dst
    const float* ew = (const float*)d_in[2];
    const float* W1 = (const float*)d_in[3]; const float* b1 = (const float*)d_in[4];
    const float* W2 = (const float*)d_in[5]; const float* b2 = (const float*)d_in[6];
    const float* W3 = (const float*)d_in[7]; const float* b3 = (const float*)d_in[8];
    float* out = (float*)d_out;

    const int* srcp = ei;
    const int* dstp = ei + NE;

    // workspace carve
    char* w = (char*)d_ws;
    size_t need = 0;
    auto carve = [&](size_t bytes) { char* p = w + need; need += alignup(bytes); return p; };
    float* dinv     = (float*)carve(NN * 4);
    int*   cnt      = (int*)  carve(NN * 4);
    int*   rowstart = (int*)  carve((NN + 1) * 4);
    int*   bsum     = (int*)  carve(NB * 4);
    int*   slot     = (int*)  carve((size_t)NE * 4);
    int2*  edat     = (int2*) carve((size_t)NE * 8);
    unsigned short* Hb  = (unsigned short*)carve((size_t)NN * NC * 2);
    unsigned short* Ab  = (unsigned short*)carve((size_t)NN * NC * 2);
    unsigned short* Xb  = (unsigned short*)carve((size_t)NN * NC * 2);
    unsigned short* Wb1 = (unsigned short*)carve(128 * 128 * 2);
    unsigned short* Wb2 = (unsigned short*)carve(128 * 128 * 2);
    unsigned short* Wb3 = (unsigned short*)carve(128 * 128 * 2);
    if (need > ws_size) return;  // workspace too small -> visible validation failure

    const int gN = (NN + 255) / 256;
    const int gE = (NE + 255) / 256;

    // CSR build; X->bf16 conversion hidden under the count atomic drain
    k_init<<<gN, 256, 0, stream>>>(cnt);
    k_count<<<GE4, 256, 0, stream>>>((const int4*)dstp, cnt, (int4*)slot,
                                     (const float4*)X, (uint4*)Xb);
    k_wconv3<<<(6144 + 255) / 256, 256, 0, stream>>>(W1, W2, W3, Wb1, Wb2, Wb3);
    k_scan1<<<NB, 256, 0, stream>>>(cnt, bsum);
    k_scan2<<<1, 64, 0, stream>>>(bsum, rowstart);
    k_scan3<<<NB, 256, 0, stream>>>(cnt, bsum, rowstart);
    // fill overlapped with layer-1 GEMM (both independent, no LDS)
    k_fillgemm1<<<GE4 + GGEMM, 256, 0, stream>>>((const int4*)srcp, (const int4*)dstp, (const float4*)ew,
                                                 rowstart, (const int4*)slot, edat, Xb, Wb1, Hb);
    k_degdinv<<<gN, 256, 0, stream>>>(rowstart, edat, dinv);
    k_norm<<<gE, 256, 0, stream>>>(dinv, edat);

    // layer 1
    k_agg<1, 1><<<GAGG, 256, 0, stream>>>(Hb, rowstart, edat, dinv, b1, Ab);
    // layer 2
    k_gemm<<<GGEMM, 256, 0, stream>>>(Ab, Wb2, Hb);
    k_agg<1, 1><<<GAGG, 256, 0, stream>>>(Hb, rowstart, edat, dinv, b2, Ab);
    // layer 3
    k_gemm<<<GGEMM, 256, 0, stream>>>(Ab, Wb3, Hb);
    k_agg<0, 0><<<GAGG, 256, 0, stream>>>(Hb, rowstart, edat, dinv, b3, out);
}